// Round 2
// baseline (29643.625 us; speedup 1.0000x reference)
//
#include <hip/hip_runtime.h>
#include <hip/hip_bf16.h>
#include <math.h>

// RSSM scan, MI355X. One persistent 128-block kernel with device-scope
// flag barriers; all per-step GEMMs fused to 6 stages; GRU gates and
// mean/std heads fused into GEMM epilogues via weight-row reordering.
// D=1024 Z=256 A=32 H=512 E=1024, T=64, B=512.

using bf16 = __hip_bfloat16;
using short8 = __attribute__((ext_vector_type(8))) short;
using f32x4 = __attribute__((ext_vector_type(4))) float;

#define GRID 128

__device__ __forceinline__ float sp_f(float x){ return x > 15.f ? x : log1pf(__expf(x)); }
__device__ __forceinline__ float sg_f(float x){ return 1.f/(1.f+__expf(-x)); }
__device__ __forceinline__ float b2f(bf16 x){ return __bfloat162float(x); }
__device__ __forceinline__ bf16  f2b(float x){ return __float2bfloat16(x); }

// swizzled LDS elem offset: [128 rows][8 slots of 8 bf16]; slot ^= row&7 (banks spread)
__device__ __forceinline__ int lds_off(int row, int slot){ return row*64 + (((slot ^ (row & 7))) << 3); }

// ---- grid barrier (arrive flags + go flag, monotonic event values) ----
__device__ __forceinline__ void gbar(int* arrive, int* go, int ev) {
  __threadfence();
  __syncthreads();
  if (blockIdx.x == 0) {
    const int t = threadIdx.x;
    if (t > 0 && t < GRID) {
      while (__hip_atomic_load(&arrive[t], __ATOMIC_ACQUIRE, __HIP_MEMORY_SCOPE_AGENT) < ev)
        __builtin_amdgcn_s_sleep(1);
    }
    __syncthreads();
    if (t == 0) __hip_atomic_store(go, ev, __ATOMIC_RELEASE, __HIP_MEMORY_SCOPE_AGENT);
  } else {
    if (threadIdx.x == 0) {
      __hip_atomic_store(&arrive[blockIdx.x], ev, __ATOMIC_RELEASE, __HIP_MEMORY_SCOPE_AGENT);
      while (__hip_atomic_load(go, __ATOMIC_ACQUIRE, __HIP_MEMORY_SCOPE_AGENT) < ev)
        __builtin_amdgcn_s_sleep(1);
    }
  }
  __syncthreads();
  __threadfence();
}

// stage a [128][64] bf16 tile from global (row stride ld) into swizzled LDS buf.
// wave w covers rows [w*32, w*32+32): 4 glds of 8 rows; source col pre-swizzled.
__device__ __forceinline__ void glds_tile(const bf16* base, int ld, bf16* buf, int w, int l) {
  const int rsub = l >> 3;
  const int slot = (l & 7) ^ rsub;           // (l&7) ^ ((row)&7) with row = w*32+i*8+rsub
  const bf16* src = base + (size_t)(w*32 + rsub)*ld + slot*8;
#pragma unroll
  for (int i = 0; i < 4; ++i)
    __builtin_amdgcn_global_load_lds((const __attribute__((address_space(1))) void*)(src + (size_t)(i*8)*ld),
                                     (__attribute__((address_space(3))) void*)(buf + (w*32 + i*8)*64),
                                     16, 0, 0);
}

__device__ __forceinline__ void mfma_tiles(f32x4 acc[4][4], const bf16* bA, const bf16* bB,
                                           int wm, int wn, int fl, int fg) {
#pragma unroll
  for (int ks = 0; ks < 2; ++ks) {
    short8 af[4], bfr[4];
#pragma unroll
    for (int i = 0; i < 4; ++i)
      af[i] = *(const short8*)(bA + lds_off(wm*64 + i*16 + fl, ks*4 + fg));
#pragma unroll
    for (int i = 0; i < 4; ++i)
      bfr[i] = *(const short8*)(bB + lds_off(wn*64 + i*16 + fl, ks*4 + fg));
#pragma unroll
    for (int mf = 0; mf < 4; ++mf)
#pragma unroll
      for (int nf = 0; nf < 4; ++nf)
        asm("v_mfma_f32_16x16x32_bf16 %0, %1, %2, %0"
            : "+v"(acc[mf][nf]) : "v"(af[mf]), "v"(bfr[nf]));
  }
}

// async k-loop: bf16 A (optionally [A0|A1] concat at k=1024), bf16 weights, dbuf + vmcnt(8)
template<bool GRUA>
__device__ __forceinline__ void kloop_async(const bf16* A0, const bf16* A1, int lda,
    const bf16* Bw, int ldb, int K, int mt, int nt, f32x4 acc[4][4],
    int w, int l, int wm, int wn, int fl, int fg,
    bf16* sA0, bf16* sA1, bf16* sB0, bf16* sB1) {
  bf16* bufA[2] = {sA0, sA1};
  bf16* bufB[2] = {sB0, sB1};
  const int nk = K >> 6;
  glds_tile(A0 + (size_t)(mt*128)*lda, lda, bufA[0], w, l);
  glds_tile(Bw + (size_t)(nt*128)*ldb, ldb, bufB[0], w, l);
#pragma unroll 1
  for (int ki = 0; ki < nk; ++ki) {
    const int kn = ki + 1;
    if (kn < nk) {
      const int k0 = kn << 6;
      const bf16* As; int kc;
      if (GRUA && k0 >= 1024) { As = A1; kc = k0 - 1024; } else { As = A0; kc = k0; }
      glds_tile(As + (size_t)(mt*128)*lda + kc, lda, bufA[kn & 1], w, l);
      glds_tile(Bw + (size_t)(nt*128)*ldb + k0, ldb, bufB[kn & 1], w, l);
      asm volatile("s_waitcnt vmcnt(8)" ::: "memory");
    } else {
      asm volatile("s_waitcnt vmcnt(0)" ::: "memory");
    }
    __builtin_amdgcn_s_barrier();
    asm volatile("" ::: "memory");
    mfma_tiles(acc, bufA[ki & 1], bufB[ki & 1], wm, wn, fl, fg);
    asm volatile("" ::: "memory");
    __builtin_amdgcn_s_barrier();
    asm volatile("" ::: "memory");
  }
}

// sync k-loop: f32 A converted via ds_write (swizzled), bf16 weights via glds
__device__ __forceinline__ void kloop_sync_f32(const float* A, int lda, const bf16* Bw, int ldb,
    int K, int mt, int nt, f32x4 acc[4][4],
    int tid, int w, int l, int wm, int wn, int fl, int fg, bf16* sA0, bf16* sB0) {
  const int nk = K >> 6;
#pragma unroll 1
  for (int ki = 0; ki < nk; ++ki) {
    const int k0 = ki << 6;
    glds_tile(Bw + (size_t)(nt*128)*ldb + k0, ldb, sB0, w, l);
#pragma unroll
    for (int i = 0; i < 4; ++i) {
      const int sid = tid + (i << 8);
      const int row = sid >> 3, s = sid & 7;
      const float* src = A + (size_t)(mt*128 + row)*lda + k0 + s*8;
      float4 a = ((const float4*)src)[0], b = ((const float4*)src)[1];
      bf16 t8[8] __attribute__((aligned(16)));
      t8[0]=f2b(a.x); t8[1]=f2b(a.y); t8[2]=f2b(a.z); t8[3]=f2b(a.w);
      t8[4]=f2b(b.x); t8[5]=f2b(b.y); t8[6]=f2b(b.z); t8[7]=f2b(b.w);
      *(short8*)(sA0 + lds_off(row, s)) = *(const short8*)t8;
    }
    asm volatile("s_waitcnt vmcnt(0) lgkmcnt(0)" ::: "memory");
    __builtin_amdgcn_s_barrier();
    asm volatile("" ::: "memory");
    mfma_tiles(acc, sA0, sB0, wm, wn, fl, fg);
    asm volatile("" ::: "memory");
    __builtin_amdgcn_s_barrier();
    asm volatile("" ::: "memory");
  }
}

// sa k-loop: A = [state*nt | action | zeropad], K=320
__device__ __forceinline__ void kloop_sa(const float* st, const float* ntp, const float* act,
    const bf16* Bw, int mt, int nt, f32x4 acc[4][4],
    int tid, int w, int l, int wm, int wn, int fl, int fg, bf16* sA0, bf16* sB0) {
#pragma unroll 1
  for (int ki = 0; ki < 5; ++ki) {
    const int k0 = ki << 6;
    glds_tile(Bw + (size_t)(nt*128)*320 + k0, 320, sB0, w, l);
#pragma unroll
    for (int i = 0; i < 4; ++i) {
      const int sid = tid + (i << 8);
      const int row = sid >> 3, s = sid & 7;
      const int rg = mt*128 + row;
      const int kg = k0 + s*8;
      float4 a = {0,0,0,0}, b = {0,0,0,0};
      if (kg < 256) {
        const float* src = st + (size_t)rg*256 + kg;
        a = ((const float4*)src)[0]; b = ((const float4*)src)[1];
        const float nv = ntp ? ntp[rg] : 1.f;
        a.x*=nv; a.y*=nv; a.z*=nv; a.w*=nv; b.x*=nv; b.y*=nv; b.z*=nv; b.w*=nv;
      } else if (kg < 288) {
        const float* src = act + (size_t)rg*32 + (kg - 256);
        a = ((const float4*)src)[0]; b = ((const float4*)src)[1];
      }
      bf16 t8[8] __attribute__((aligned(16)));
      t8[0]=f2b(a.x); t8[1]=f2b(a.y); t8[2]=f2b(a.z); t8[3]=f2b(a.w);
      t8[4]=f2b(b.x); t8[5]=f2b(b.y); t8[6]=f2b(b.z); t8[7]=f2b(b.w);
      *(short8*)(sA0 + lds_off(row, s)) = *(const short8*)t8;
    }
    asm volatile("s_waitcnt vmcnt(0) lgkmcnt(0)" ::: "memory");
    __builtin_amdgcn_s_barrier();
    asm volatile("" ::: "memory");
    mfma_tiles(acc, sA0, sB0, wm, wn, fl, fg);
    asm volatile("" ::: "memory");
    __builtin_amdgcn_s_barrier();
    asm volatile("" ::: "memory");
  }
}

// ---- epilogues (C/D layout m89: col = fl, row = fg*4 + r per 16x16 frag) ----
template<bool RELU, bool ADD>
__device__ __forceinline__ void epi_bf16(const f32x4 acc[4][4], bf16* dst, int ldc,
    const float* bias, const bf16* addm, int lda2, int mt, int nt, int wm, int wn, int fl, int fg) {
#pragma unroll
  for (int mf = 0; mf < 4; ++mf)
#pragma unroll
    for (int nf = 0; nf < 4; ++nf) {
      const int col = nt*128 + wn*64 + nf*16 + fl;
      const float bv = bias ? bias[col] : 0.f;
#pragma unroll
      for (int r = 0; r < 4; ++r) {
        const int row = mt*128 + wm*64 + mf*16 + fg*4 + r;
        float v = acc[mf][nf][r] + bv;
        if (ADD) v += b2f(addm[(size_t)row*lda2 + col]);
        if (RELU) v = v > 0.f ? v : 0.f;
        dst[(size_t)row*ldc + col] = f2b(v);
      }
    }
}

__device__ __forceinline__ void epi_gru(const f32x4 acc[4][4], const float* bg,
    const bf16* bel, bf16* rnn, int mt, int nt, int wm, int wn, int fl, int fg) {
  const int cb = nt*128 + wn*64;
  const int j = nt*32 + wn*16 + fl;
  const float b0 = bg[cb + fl], b1 = bg[cb + 16 + fl], b2 = bg[cb + 32 + fl], b3 = bg[cb + 48 + fl];
#pragma unroll
  for (int mf = 0; mf < 4; ++mf)
#pragma unroll
    for (int r = 0; r < 4; ++r) {
      const int row = mt*128 + wm*64 + mf*16 + fg*4 + r;
      const float a0 = acc[mf][0][r] + b0;
      const float a1 = acc[mf][1][r] + b1;
      const float a2 = acc[mf][2][r] + b2;
      const float a3 = acc[mf][3][r] + b3;
      const float rr = sg_f(a0), zz = sg_f(a1);
      const float nn = tanhf(a2 + rr*a3);
      const float h = b2f(bel[(size_t)row*1024 + j]);
      rnn[(size_t)row*1024 + j] = f2b((1.f - zz)*nn + zz*h);
    }
}

__device__ __forceinline__ void epi_bq(const f32x4 acc[4][4], const float* bb,
    const float* nb, float* obel, bf16* belbf, int mt, int nt, int wm, int wn, int fl, int fg) {
  const int cb = nt*128 + wn*64;
#pragma unroll
  for (int g = 0; g < 2; ++g) {
    const int j = nt*64 + (wn*2 + g)*16 + fl;
    const float bm = bb[cb + g*32 + fl];
    const float bs = bb[cb + g*32 + 16 + fl];
#pragma unroll
    for (int mf = 0; mf < 4; ++mf)
#pragma unroll
      for (int r = 0; r < 4; ++r) {
        const int row = mt*128 + wm*64 + mf*16 + fg*4 + r;
        const float mean = acc[mf][2*g][r] + bm;
        const float sd = sp_f(acc[mf][2*g+1][r] + bs) + 0.1f;
        const float bl = mean + sd * nb[(size_t)row*1024 + j];
        obel[(size_t)row*1024 + j] = bl;
        belbf[(size_t)row*1024 + j] = f2b(bl);
      }
  }
}

__device__ __forceinline__ void epi_qp(const f32x4 acc[4][4], const float* bb, const float* noise,
    float* om, float* os, float* ost, int mt, int nt, int wm, int wn, int fl, int fg) {
  const int cb = nt*128 + wn*64;
#pragma unroll
  for (int g = 0; g < 2; ++g) {
    const int j = nt*64 + (wn*2 + g)*16 + fl;
    const float bm = bb[cb + g*32 + fl];
    const float bs = bb[cb + g*32 + 16 + fl];
#pragma unroll
    for (int mf = 0; mf < 4; ++mf)
#pragma unroll
      for (int r = 0; r < 4; ++r) {
        const int row = mt*128 + wm*64 + mf*16 + fg*4 + r;
        const float mean = acc[mf][2*g][r] + bm;
        const float sd = sp_f(acc[mf][2*g+1][r] + bs) + 0.1f;
        const size_t o = (size_t)row*256 + j;
        om[o] = mean; os[o] = sd; ost[o] = mean + sd*noise[o];
      }
  }
}

struct PP {
  const float *prev_state, *prev_belief, *actions, *obs, *nonterm, *nb, *np, *nq;
  const float *b_sa, *b_eb, *b_ebq, *b_ebp;
  const bf16 *w_sa, *w_gru, *w_eb, *w_bq, *w_ebq, *w_sq, *w_ebp, *w_sp;
  const float *bg, *bbq, *bsq, *bsp;
  bf16 *obs_c, *deter, *bel, *rnn, *sh, *shq, *shp;
  float *o_bel, *o_pst, *o_pm, *o_psd, *o_qst, *o_qm, *o_qsd;
  int *arrive; int *go;
};

__global__ __launch_bounds__(256) void persist_k(PP p) {
  __shared__ bf16 sA[2][8192];
  __shared__ bf16 sB[2][8192];
  const int bid = blockIdx.x, tid = threadIdx.x;
  const int l = tid & 63, w = tid >> 6;
  const int wm = w >> 1, wn = w & 1, fl = l & 15, fg = l >> 4;
  int ev = 1;

  // init belief carry (bf16) from prev_belief
#pragma unroll 1
  for (int i = bid*256 + tid; i < 65536; i += GRID*256) {
    float4 a = ((const float4*)p.prev_belief)[i*2];
    float4 b = ((const float4*)p.prev_belief)[i*2 + 1];
    bf16 t8[8] __attribute__((aligned(16)));
    t8[0]=f2b(a.x); t8[1]=f2b(a.y); t8[2]=f2b(a.z); t8[3]=f2b(a.w);
    t8[4]=f2b(b.x); t8[5]=f2b(b.y); t8[6]=f2b(b.z); t8[7]=f2b(b.w);
    ((short8*)p.bel)[i] = *(const short8*)t8;
  }
  // obs contribution: obs_c = obs @ W_ebq[:,1024:].T + b_ebq (bf16, no relu)
#pragma unroll 1
  for (int tt = bid; tt < 1024; tt += GRID) {
    const int mt = tt >> 2, nt = tt & 3;
    f32x4 acc[4][4] = {};
    kloop_sync_f32(p.obs, 1024, p.w_ebq + 1024, 2048, 1024, mt, nt, acc,
                   tid, w, l, wm, wn, fl, fg, sA[0], sB[0]);
    epi_bf16<false,false>(acc, p.obs_c, 512, p.b_ebq, nullptr, 0, mt, nt, wm, wn, fl, fg);
  }
  gbar(p.arrive, p.go, ev++);

#pragma unroll 1
  for (int t = 0; t < 64; ++t) {
    // 1. deter = relu([q_state*nt | a] @ W_sa.T + b_sa)
    if (bid < 32) {
      const int mt = bid >> 3, nt = bid & 7;
      f32x4 acc[4][4] = {};
      const float* ss  = t ? (p.o_qst + (size_t)(t-1)*131072) : p.prev_state;
      const float* ntp = t ? (p.nonterm + (size_t)(t-1)*512) : nullptr;
      kloop_sa(ss, ntp, p.actions + (size_t)t*16384, p.w_sa, mt, nt, acc,
               tid, w, l, wm, wn, fl, fg, sA[0], sB[0]);
      epi_bf16<true,false>(acc, p.deter, 1024, p.b_sa, nullptr, 0, mt, nt, wm, wn, fl, fg);
    }
    gbar(p.arrive, p.go, ev++);
    // 2. GRU fused: [deter|bel] @ Wgru'.T -> gates -> rnn
    {
      const int mt = bid >> 5, nt = bid & 31;
      f32x4 acc[4][4] = {};
      kloop_async<true>(p.deter, p.bel, 1024, p.w_gru, 2048, 2048, mt, nt, acc,
                        w, l, wm, wn, fl, fg, sA[0], sA[1], sB[0], sB[1]);
      epi_gru(acc, p.bg, p.bel, p.rnn, mt, nt, wm, wn, fl, fg);
    }
    gbar(p.arrive, p.go, ev++);
    // 3. sh = relu(rnn @ W_eb.T + b_eb)
    if (bid < 16) {
      const int mt = bid >> 2, nt = bid & 3;
      f32x4 acc[4][4] = {};
      kloop_async<false>(p.rnn, nullptr, 1024, p.w_eb, 1024, 1024, mt, nt, acc,
                         w, l, wm, wn, fl, fg, sA[0], sA[1], sB[0], sB[1]);
      epi_bf16<true,false>(acc, p.sh, 512, p.b_eb, nullptr, 0, mt, nt, wm, wn, fl, fg);
    }
    gbar(p.arrive, p.go, ev++);
    // 4. belief = mean + (softplus(std)+0.1)*noise  (paired W_bq')
    if (bid < 64) {
      const int mt = bid >> 4, nt = bid & 15;
      f32x4 acc[4][4] = {};
      kloop_async<false>(p.sh, nullptr, 512, p.w_bq, 512, 512, mt, nt, acc,
                         w, l, wm, wn, fl, fg, sA[0], sA[1], sB[0], sB[1]);
      epi_bq(acc, p.bbq, p.nb + (size_t)t*524288, p.o_bel + (size_t)t*524288, p.bel,
             mt, nt, wm, wn, fl, fg);
    }
    gbar(p.arrive, p.go, ev++);
    // 5. shq = relu(bel @ W_ebq[:,:1024].T + obs_c[t])
    if (bid < 16) {
      const int mt = bid >> 2, nt = bid & 3;
      f32x4 acc[4][4] = {};
      kloop_async<false>(p.bel, nullptr, 1024, p.w_ebq, 2048, 1024, mt, nt, acc,
                         w, l, wm, wn, fl, fg, sA[0], sA[1], sB[0], sB[1]);
      epi_bf16<true,true>(acc, p.shq, 512, nullptr, p.obs_c + (size_t)t*262144, 512,
                          mt, nt, wm, wn, fl, fg);
    }
    gbar(p.arrive, p.go, ev++);
    // 6. q head (paired W_sq')
    if (bid < 16) {
      const int mt = bid >> 2, nt = bid & 3;
      f32x4 acc[4][4] = {};
      kloop_async<false>(p.shq, nullptr, 512, p.w_sq, 512, 512, mt, nt, acc,
                         w, l, wm, wn, fl, fg, sA[0], sA[1], sB[0], sB[1]);
      epi_qp(acc, p.bsq, p.nq + (size_t)t*131072,
             p.o_qm + (size_t)t*131072, p.o_qsd + (size_t)t*131072, p.o_qst + (size_t)t*131072,
             mt, nt, wm, wn, fl, fg);
    }
    gbar(p.arrive, p.go, ev++);
  }

  // prior: shp = relu(beliefs @ W_ebp.T + b_ebp)  (shp lives in p_state region)
#pragma unroll 1
  for (int tt = bid; tt < 1024; tt += GRID) {
    const int mt = tt >> 2, nt = tt & 3;
    f32x4 acc[4][4] = {};
    kloop_sync_f32(p.o_bel, 1024, p.w_ebp, 1024, 1024, mt, nt, acc,
                   tid, w, l, wm, wn, fl, fg, sA[0], sB[0]);
    epi_bf16<true,false>(acc, p.shp, 512, p.b_ebp, nullptr, 0, mt, nt, wm, wn, fl, fg);
  }
  gbar(p.arrive, p.go, ev++);
  // p head in 8 chunks of 4096 rows; register-carry barrier lets p_state writes
  // safely overwrite consumed shp rows (same byte ranges, row-staggered).
#pragma unroll 1
  for (int c = 0; c < 8; ++c) {
    const int mt = c*32 + (bid >> 2), nt = bid & 3;
    f32x4 acc[4][4] = {};
    kloop_async<false>(p.shp, nullptr, 512, p.w_sp, 512, 512, mt, nt, acc,
                       w, l, wm, wn, fl, fg, sA[0], sA[1], sB[0], sB[1]);
    gbar(p.arrive, p.go, ev++);
    epi_qp(acc, p.bsp, p.np, p.o_pm, p.o_psd, p.o_pst, mt, nt, wm, wn, fl, fg);
  }
}

// ---- prep kernels ----
__global__ __launch_bounds__(256) void k_cvt8(const float* __restrict__ s, bf16* __restrict__ d, int n8) {
  int i = blockIdx.x*256 + threadIdx.x;
  if (i >= n8) return;
  float4 a = ((const float4*)s)[i*2], b = ((const float4*)s)[i*2+1];
  bf16 t8[8] __attribute__((aligned(16)));
  t8[0]=f2b(a.x); t8[1]=f2b(a.y); t8[2]=f2b(a.z); t8[3]=f2b(a.w);
  t8[4]=f2b(b.x); t8[5]=f2b(b.y); t8[6]=f2b(b.z); t8[7]=f2b(b.w);
  ((short8*)d)[i] = *(const short8*)t8;
}

__global__ __launch_bounds__(256) void k_wsa(const float* __restrict__ W, bf16* __restrict__ dst) {
  int i = blockIdx.x*256 + threadIdx.x;
  if (i >= 40960) return;
  int e = i*8, r = e/320, c = e - r*320;
  bf16 t8[8] __attribute__((aligned(16)));
  if (c < 288) {
    const float* s = W + (size_t)r*288 + c;
    float4 a = ((const float4*)s)[0], b = ((const float4*)s)[1];
    t8[0]=f2b(a.x); t8[1]=f2b(a.y); t8[2]=f2b(a.z); t8[3]=f2b(a.w);
    t8[4]=f2b(b.x); t8[5]=f2b(b.y); t8[6]=f2b(b.z); t8[7]=f2b(b.w);
  } else {
    for (int q = 0; q < 8; ++q) t8[q] = f2b(0.f);
  }
  *(short8*)(dst + e) = *(const short8*)t8;
}

__global__ __launch_bounds__(256) void k_gru_r(const float* __restrict__ Wih, const float* __restrict__ Whh,
                                               bf16* __restrict__ dst) {
  int idx = blockIdx.x*256 + threadIdx.x;
  if (idx >= 2097152) return;
  int rp = idx >> 9;
  int c4 = (idx & 511) << 2;
  int nt = rp >> 7, id = rp & 127;
  int wn2 = (id >> 6) & 1, nf = (id >> 4) & 3, fl2 = id & 15;
  int j = nt*32 + wn2*16 + fl2;
  float4 v = {0,0,0,0};
  if (c4 < 1024) {
    int srow = (nf==0) ? j : (nf==1) ? 1024+j : (nf==2) ? 2048+j : -1;
    if (srow >= 0) v = *(const float4*)(Wih + (size_t)srow*1024 + c4);
  } else {
    int srow = (nf==0) ? j : (nf==1) ? 1024+j : (nf==3) ? 2048+j : -1;
    if (srow >= 0) v = *(const float4*)(Whh + (size_t)srow*1024 + (c4-1024));
  }
  bf16 t4[4] __attribute__((aligned(8)));
  t4[0]=f2b(v.x); t4[1]=f2b(v.y); t4[2]=f2b(v.z); t4[3]=f2b(v.w);
  *(uint2*)(dst + (size_t)rp*2048 + c4) = *(const uint2*)t4;
}

__global__ __launch_bounds__(256) void k_pair(const float* __restrict__ src, bf16* __restrict__ dst,
                                              int halfN, int n) {
  int idx = blockIdx.x*256 + threadIdx.x;
  if (idx >= n) return;
  int rp = idx >> 7;
  int c4 = (idx & 127) << 2;
  int nt = rp >> 7, id = rp & 127;
  int pb = (id >> 5) & 3, comp = (id >> 4) & 1, fl2 = id & 15;
  int j = nt*64 + pb*16 + fl2;
  int srow = comp*halfN + j;
  float4 v = *(const float4*)(src + (size_t)srow*512 + c4);
  bf16 t4[4] __attribute__((aligned(8)));
  t4[0]=f2b(v.x); t4[1]=f2b(v.y); t4[2]=f2b(v.z); t4[3]=f2b(v.w);
  *(uint2*)(dst + (size_t)rp*512 + c4) = *(const uint2*)t4;
}

__global__ __launch_bounds__(256) void k_bias(const float* b_ih, const float* b_hh, const float* b_bq,
                                              const float* b_sq, const float* b_sp,
                                              float* bg, float* bbq, float* bsq, float* bsp) {
  for (int i = threadIdx.x; i < 4096; i += 256) {
    int nt = i >> 7, id = i & 127;
    int wn2 = (id >> 6) & 1, nf = (id >> 4) & 3, fl2 = id & 15;
    int j = nt*32 + wn2*16 + fl2;
    float v;
    if (nf == 0) v = b_ih[j] + b_hh[j];
    else if (nf == 1) v = b_ih[1024+j] + b_hh[1024+j];
    else if (nf == 2) v = b_ih[2048+j];
    else v = b_hh[2048+j];
    bg[i] = v;
  }
  for (int i = threadIdx.x; i < 2048; i += 256) {
    int nt = i >> 7, id = i & 127, pb = (id >> 5) & 3, comp = (id >> 4) & 1, fl2 = id & 15;
    int j = nt*64 + pb*16 + fl2;
    bbq[i] = b_bq[comp*1024 + j];
  }
  for (int i = threadIdx.x; i < 512; i += 256) {
    int nt = i >> 7, id = i & 127, pb = (id >> 5) & 3, comp = (id >> 4) & 1, fl2 = id & 15;
    int j = nt*64 + pb*16 + fl2;
    bsq[i] = b_sq[comp*256 + j];
    bsp[i] = b_sp[comp*256 + j];
  }
}

extern "C" void kernel_launch(void* const* d_in, const int* in_sizes, int n_in,
                              void* d_out, int out_size, void* d_ws, size_t ws_size,
                              hipStream_t stream) {
  const float* prev_state   = (const float*)d_in[0];
  const float* prev_belief  = (const float*)d_in[1];
  const float* actions      = (const float*)d_in[2];
  const float* observations = (const float*)d_in[3];
  const float* nonterm      = (const float*)d_in[4];
  const float* noise_belief = (const float*)d_in[5];
  const float* noise_prior  = (const float*)d_in[6];
  const float* noise_post   = (const float*)d_in[7];
  const float* W_sa  = (const float*)d_in[8];  const float* b_sa  = (const float*)d_in[9];
  const float* W_ih  = (const float*)d_in[10]; const float* b_ih  = (const float*)d_in[11];
  const float* W_hh  = (const float*)d_in[12]; const float* b_hh  = (const float*)d_in[13];
  const float* W_eb  = (const float*)d_in[14]; const float* b_eb  = (const float*)d_in[15];
  const float* W_bq  = (const float*)d_in[16]; const float* b_bq  = (const float*)d_in[17];
  const float* W_ebp = (const float*)d_in[18]; const float* b_ebp = (const float*)d_in[19];
  const float* W_sp  = (const float*)d_in[20]; const float* b_sp  = (const float*)d_in[21];
  const float* W_ebq = (const float*)d_in[22]; const float* b_ebq = (const float*)d_in[23];
  const float* W_sq  = (const float*)d_in[24]; const float* b_sq  = (const float*)d_in[25];

  float* out = (float*)d_out;
  char* ws = (char*)d_ws;

  // ws layout
  int* arrive = (int*)ws;
  int* go     = (int*)(ws + 512);
  float* bg   = (float*)(ws + 1024);
  float* bbq  = bg + 4096;
  float* bsq  = bbq + 2048;
  float* bsp  = bsq + 512;
  bf16* wb    = (bf16*)(ws + 32768);
  bf16* w_sa  = wb;                 // [1024][320]
  bf16* w_gru = wb + 327680;        // [4096][2048]
  bf16* w_eb  = wb + 8716288;       // [512][1024]
  bf16* w_bq  = wb + 9240576;       // [2048][512]
  bf16* w_ebq = wb + 10289152;      // [512][2048]
  bf16* w_sq  = wb + 11337728;      // [512][512]
  bf16* w_ebp = wb + 11599872;      // [512][1024]
  bf16* w_sp  = wb + 12124160;      // [512][512]  (ws end ~24.8MB)

  // out-region scratch (element offsets in f32)
  float* o_bel = out;
  float* o_pst = out + 33554432;
  float* o_pm  = out + 41943040;
  float* o_psd = out + 50331648;
  float* o_qst = out + 58720256;
  float* o_qm  = out + 67108864;
  float* o_qsd = out + 75497472;
  bf16* obs_c = (bf16*)o_pm;        // [64*512][512] bf16 (dead before pm written)
  bf16* shp   = (bf16*)o_pst;       // [32768][512] bf16 (overwritten row-staggered)
  bf16* deter = (bf16*)o_psd;       // activations in psd region (dead before psd written)
  bf16* belb  = deter + 524288;
  bf16* rnn   = belb + 524288;
  bf16* sh    = rnn + 524288;
  bf16* shq   = sh + 262144;

  hipMemsetAsync(ws, 0, 1024, stream);
  k_wsa  <<<160, 256, 0, stream>>>(W_sa, w_sa);
  k_gru_r<<<8192, 256, 0, stream>>>(W_ih, W_hh, w_gru);
  k_cvt8 <<<256, 256, 0, stream>>>(W_eb, w_eb, 65536);
  k_pair <<<1024, 256, 0, stream>>>(W_bq, w_bq, 1024, 262144);
  k_cvt8 <<<512, 256, 0, stream>>>(W_ebq, w_ebq, 131072);
  k_pair <<<256, 256, 0, stream>>>(W_sq, w_sq, 256, 65536);
  k_cvt8 <<<256, 256, 0, stream>>>(W_ebp, w_ebp, 65536);
  k_pair <<<256, 256, 0, stream>>>(W_sp, w_sp, 256, 65536);
  k_bias <<<1, 256, 0, stream>>>(b_ih, b_hh, b_bq, b_sq, b_sp, bg, bbq, bsq, bsp);

  PP p;
  p.prev_state = prev_state; p.prev_belief = prev_belief; p.actions = actions;
  p.obs = observations; p.nonterm = nonterm; p.nb = noise_belief; p.np = noise_prior; p.nq = noise_post;
  p.b_sa = b_sa; p.b_eb = b_eb; p.b_ebq = b_ebq; p.b_ebp = b_ebp;
  p.w_sa = w_sa; p.w_gru = w_gru; p.w_eb = w_eb; p.w_bq = w_bq;
  p.w_ebq = w_ebq; p.w_sq = w_sq; p.w_ebp = w_ebp; p.w_sp = w_sp;
  p.bg = bg; p.bbq = bbq; p.bsq = bsq; p.bsp = bsp;
  p.obs_c = obs_c; p.deter = deter; p.bel = belb; p.rnn = rnn; p.sh = sh; p.shq = shq; p.shp = shp;
  p.o_bel = o_bel; p.o_pst = o_pst; p.o_pm = o_pm; p.o_psd = o_psd;
  p.o_qst = o_qst; p.o_qm = o_qm; p.o_qsd = o_qsd;
  p.arrive = arrive; p.go = go;

  persist_k<<<GRID, 256, 0, stream>>>(p);
}

// Round 6
// 18953.152 us; speedup vs baseline: 1.5640x; 1.5640x over previous
//
#include <hip/hip_runtime.h>
#include <hip/hip_bf16.h>
#include <math.h>

// RSSM scan, MI355X. Persistent 128-block kernel = R2's PASSED kernel with
// exactly two changes: (1) barrier polls are RELAXED (fences stay: full
// __threadfence on entry+exit -- fence/fence synchronization, no per-poll
// buffer_inv storm); (2) scan partitioned into 4 independent groups of 32
// blocks (128 batch rows each) so per-step barriers are group-local.
// All data ops are PLAIN loads/stores (no sc bits, no XCD assumptions).
// D=1024 Z=256 A=32 H=512 E=1024, T=64, B=512.

using bf16 = __hip_bfloat16;
using short8 = __attribute__((ext_vector_type(8))) short;
using f32x4 = __attribute__((ext_vector_type(4))) float;

#define GRID 128

__device__ __forceinline__ float sp_f(float x){ return x > 15.f ? x : log1pf(__expf(x)); }
__device__ __forceinline__ float sg_f(float x){ return 1.f/(1.f+__expf(-x)); }
__device__ __forceinline__ float b2f(bf16 x){ return __bfloat162float(x); }
__device__ __forceinline__ bf16  f2b(float x){ return __float2bfloat16(x); }

// swizzled LDS elem offset: [128 rows][8 slots of 8 bf16]; slot ^= row&7
__device__ __forceinline__ int lds_off(int row, int slot){ return row*64 + ((slot ^ (row & 7)) << 3); }

// ---- barrier: full fences (R2-proven), RELAXED polls (the only change) ----
__device__ __forceinline__ void fence_bar(int* fl, int n, int me, int ev) {
  __threadfence();                       // release side: every wave drains + wbl2
  __syncthreads();
  if (threadIdx.x == 0)
    __hip_atomic_store(&fl[me], ev, __ATOMIC_RELAXED, __HIP_MEMORY_SCOPE_AGENT);
  if ((int)threadIdx.x < n && (int)threadIdx.x != me) {
    while (__hip_atomic_load(&fl[threadIdx.x], __ATOMIC_RELAXED, __HIP_MEMORY_SCOPE_AGENT) < ev)
      __builtin_amdgcn_s_sleep(2);
  }
  __syncthreads();
  __threadfence();                       // acquire side: every wave invalidates
}

// stage a [128][64] bf16 tile from global (plain cached) into swizzled LDS
__device__ __forceinline__ void glds_tile(const bf16* base, int ld, bf16* buf, int w, int l) {
  const int rsub = l >> 3;
  const int slot = (l & 7) ^ rsub;
  const bf16* src = base + (size_t)(w*32 + rsub)*ld + slot*8;
#pragma unroll
  for (int i = 0; i < 4; ++i)
    __builtin_amdgcn_global_load_lds((const __attribute__((address_space(1))) void*)(src + (size_t)(i*8)*ld),
                                     (__attribute__((address_space(3))) void*)(buf + (w*32 + i*8)*64),
                                     16, 0, 0);
}

__device__ __forceinline__ void mfma_tiles(f32x4 acc[4][4], const bf16* bA, const bf16* bB,
                                           int wm, int wn, int fl, int fg) {
#pragma unroll
  for (int ks = 0; ks < 2; ++ks) {
    short8 af[4], bfr[4];
#pragma unroll
    for (int i = 0; i < 4; ++i)
      af[i] = *(const short8*)(bA + lds_off(wm*64 + i*16 + fl, ks*4 + fg));
#pragma unroll
    for (int i = 0; i < 4; ++i)
      bfr[i] = *(const short8*)(bB + lds_off(wn*64 + i*16 + fl, ks*4 + fg));
#pragma unroll
    for (int mf = 0; mf < 4; ++mf)
#pragma unroll
      for (int nf = 0; nf < 4; ++nf)
        asm("v_mfma_f32_16x16x32_bf16 %0, %1, %2, %0"
            : "+v"(acc[mf][nf]) : "v"(af[mf]), "v"(bfr[nf]));
  }
}

// ---- k-loop: bf16 A via glds (plain), dbuf, counted vmcnt (R2-proven) ----
// A optionally [A0|A1] concat at k=1024 (GRU). rbase = global row offset.
template<bool GRUA>
__device__ __forceinline__ void kloop_async(const bf16* A0, const bf16* A1, int lda,
    const bf16* Bw, int ldb, int K, int rbase, int nt, f32x4 acc[4][4],
    int w, int l, int wm, int wn, int fl, int fg,
    bf16* sA0, bf16* sA1, bf16* sB0, bf16* sB1) {
  bf16* bufA[2] = {sA0, sA1};
  bf16* bufB[2] = {sB0, sB1};
  const int nk = K >> 6;
  glds_tile(A0 + (size_t)rbase*lda, lda, bufA[0], w, l);
  glds_tile(Bw + (size_t)(nt*128)*ldb, ldb, bufB[0], w, l);
#pragma unroll 1
  for (int ki = 0; ki < nk; ++ki) {
    const int kn = ki + 1;
    if (kn < nk) {
      const int k0 = kn << 6;
      const bf16* As = A0; int kc = k0;
      if (GRUA && k0 >= 1024) { As = A1; kc = k0 - 1024; }
      glds_tile(As + (size_t)rbase*lda + kc, lda, bufA[kn & 1], w, l);
      glds_tile(Bw + (size_t)(nt*128)*ldb + k0, ldb, bufB[kn & 1], w, l);
      asm volatile("s_waitcnt vmcnt(8)" ::: "memory");
    } else {
      asm volatile("s_waitcnt vmcnt(0)" ::: "memory");
    }
    __builtin_amdgcn_s_barrier();
    mfma_tiles(acc, bufA[ki & 1], bufB[ki & 1], wm, wn, fl, fg);
    __builtin_amdgcn_s_barrier();
  }
}

// ---- sa k-loop: A = [q_state*nt | action | zero-pad], K=320, plain loads ----
__device__ __forceinline__ void kloop_sa(const float* st, const float* ntp, const float* act,
    const bf16* Bw, int rbase, int nt, f32x4 acc[4][4],
    int tid, int w, int l, int wm, int wn, int fl, int fg, bf16* sA0, bf16* sB0) {
#pragma unroll 1
  for (int ki = 0; ki < 5; ++ki) {
    const int k0 = ki << 6;
    glds_tile(Bw + (size_t)(nt*128)*320 + k0, 320, sB0, w, l);
#pragma unroll
    for (int i = 0; i < 4; ++i) {
      const int sid = tid + (i << 8);
      const int row = sid >> 3, s = sid & 7;
      const int rg = rbase + row;
      const int kg = k0 + s*8;
      float4 a = {0,0,0,0}, b = {0,0,0,0};
      if (kg < 256) {
        const float* src = st + (size_t)rg*256 + kg;
        a = ((const float4*)src)[0]; b = ((const float4*)src)[1];
        const float nv = ntp ? ntp[rg] : 1.f;
        a.x*=nv; a.y*=nv; a.z*=nv; a.w*=nv; b.x*=nv; b.y*=nv; b.z*=nv; b.w*=nv;
      } else if (kg < 288) {
        const float* src = act + (size_t)rg*32 + (kg - 256);
        a = ((const float4*)src)[0]; b = ((const float4*)src)[1];
      }
      bf16 t8[8] __attribute__((aligned(16)));
      t8[0]=f2b(a.x); t8[1]=f2b(a.y); t8[2]=f2b(a.z); t8[3]=f2b(a.w);
      t8[4]=f2b(b.x); t8[5]=f2b(b.y); t8[6]=f2b(b.z); t8[7]=f2b(b.w);
      *(short8*)(sA0 + lds_off(row, s)) = *(const short8*)t8;
    }
    asm volatile("s_waitcnt vmcnt(0) lgkmcnt(0)" ::: "memory");
    __builtin_amdgcn_s_barrier();
    mfma_tiles(acc, sA0, sB0, wm, wn, fl, fg);
    __builtin_amdgcn_s_barrier();
  }
}

// ---- plain k-loop (p-head): A bf16 via glds, double-buffered ----
__device__ __forceinline__ void kloop_plain(const bf16* A0, int lda,
    const bf16* Bw, int ldb, int K, int rbase, int nt, f32x4 acc[4][4],
    int w, int l, int wm, int wn, int fl, int fg,
    bf16* sA0, bf16* sA1, bf16* sB0, bf16* sB1) {
  bf16* bufA[2] = {sA0, sA1};
  bf16* bufB[2] = {sB0, sB1};
  const int nk = K >> 6;
  glds_tile(A0 + (size_t)rbase*lda, lda, bufA[0], w, l);
  glds_tile(Bw + (size_t)(nt*128)*ldb, ldb, bufB[0], w, l);
#pragma unroll 1
  for (int ki = 0; ki < nk; ++ki) {
    const int kn = ki + 1;
    if (kn < nk) {
      const int k0 = kn << 6;
      glds_tile(A0 + (size_t)rbase*lda + k0, lda, bufA[kn & 1], w, l);
      glds_tile(Bw + (size_t)(nt*128)*ldb + k0, ldb, bufB[kn & 1], w, l);
      asm volatile("s_waitcnt vmcnt(8)" ::: "memory");
    } else {
      asm volatile("s_waitcnt vmcnt(0)" ::: "memory");
    }
    __builtin_amdgcn_s_barrier();
    mfma_tiles(acc, bufA[ki & 1], bufB[ki & 1], wm, wn, fl, fg);
    __builtin_amdgcn_s_barrier();
  }
}

// ---- sync f32 k-loop (prologue obs_c / prior shp): plain cached A ----
__device__ __forceinline__ void kloop_sync_f32(const float* A, int lda, const bf16* Bw, int ldb,
    int K, int rbase, int nt, f32x4 acc[4][4],
    int tid, int w, int l, int wm, int wn, int fl, int fg, bf16* sA0, bf16* sB0) {
  const int nk = K >> 6;
#pragma unroll 1
  for (int ki = 0; ki < nk; ++ki) {
    const int k0 = ki << 6;
    glds_tile(Bw + (size_t)(nt*128)*ldb + k0, ldb, sB0, w, l);
#pragma unroll
    for (int i = 0; i < 4; ++i) {
      const int sid = tid + (i << 8);
      const int row = sid >> 3, s = sid & 7;
      const float* src = A + (size_t)(rbase + row)*lda + k0 + s*8;
      float4 a = ((const float4*)src)[0], b = ((const float4*)src)[1];
      bf16 t8[8] __attribute__((aligned(16)));
      t8[0]=f2b(a.x); t8[1]=f2b(a.y); t8[2]=f2b(a.z); t8[3]=f2b(a.w);
      t8[4]=f2b(b.x); t8[5]=f2b(b.y); t8[6]=f2b(b.z); t8[7]=f2b(b.w);
      *(short8*)(sA0 + lds_off(row, s)) = *(const short8*)t8;
    }
    asm volatile("s_waitcnt vmcnt(0) lgkmcnt(0)" ::: "memory");
    __builtin_amdgcn_s_barrier();
    mfma_tiles(acc, sA0, sB0, wm, wn, fl, fg);
    __builtin_amdgcn_s_barrier();
  }
}

// ---- epilogues (C/D layout m89: col=fl, row=fg*4+r per 16x16 frag) ----
template<bool RELU, bool ADD>
__device__ __forceinline__ void epi_b16(const f32x4 acc[4][4], bf16* dst, int ldc,
    const float* bias, const bf16* addm, int ldadd, int rbase, int nt,
    int wm, int wn, int fl, int fg) {
#pragma unroll
  for (int mf = 0; mf < 4; ++mf)
#pragma unroll
    for (int nf = 0; nf < 4; ++nf) {
      const int col = nt*128 + wn*64 + nf*16 + fl;
      const float bv = bias ? bias[col] : 0.f;
#pragma unroll
      for (int r = 0; r < 4; ++r) {
        const int row = rbase + wm*64 + mf*16 + fg*4 + r;
        float v = acc[mf][nf][r] + bv;
        if (ADD) v += b2f(addm[(size_t)row*ldadd + col]);
        if (RELU) v = v > 0.f ? v : 0.f;
        dst[(size_t)row*ldc + col] = f2b(v);
      }
    }
}

__device__ __forceinline__ void epi_gru(const f32x4 acc[4][4], const float* bg,
    const bf16* bel, bf16* rnn, int rbase, int nt, int wm, int wn, int fl, int fg) {
  const int cb = nt*128 + wn*64;
  const int j = nt*32 + wn*16 + fl;
  const float b0 = bg[cb + fl], b1 = bg[cb+16+fl], b2 = bg[cb+32+fl], b3 = bg[cb+48+fl];
#pragma unroll
  for (int mf = 0; mf < 4; ++mf)
#pragma unroll
    for (int r = 0; r < 4; ++r) {
      const int row = rbase + wm*64 + mf*16 + fg*4 + r;
      const float a0 = acc[mf][0][r] + b0;
      const float a1 = acc[mf][1][r] + b1;
      const float a2 = acc[mf][2][r] + b2;
      const float a3 = acc[mf][3][r] + b3;
      const float rr = sg_f(a0), zz = sg_f(a1);
      const float nn = tanhf(a2 + rr*a3);
      const float h = b2f(bel[(size_t)row*1024 + j]);
      rnn[(size_t)row*1024 + j] = f2b((1.f - zz)*nn + zz*h);
    }
}

__device__ __forceinline__ void epi_bq(const f32x4 acc[4][4], const float* bb,
    const float* nb, float* obel, bf16* belbf, int rbase, int nt,
    int wm, int wn, int fl, int fg) {
  const int cb = nt*128 + wn*64;
#pragma unroll
  for (int gg = 0; gg < 2; ++gg) {
    const int j = nt*64 + (wn*2 + gg)*16 + fl;
    const float bm = bb[cb + gg*32 + fl];
    const float bs = bb[cb + gg*32 + 16 + fl];
#pragma unroll
    for (int mf = 0; mf < 4; ++mf)
#pragma unroll
      for (int r = 0; r < 4; ++r) {
        const int row = rbase + wm*64 + mf*16 + fg*4 + r;
        const float mean = acc[mf][2*gg][r] + bm;
        const float sd = sp_f(acc[mf][2*gg+1][r] + bs) + 0.1f;
        const float bl = mean + sd * nb[(size_t)row*1024 + j];
        obel[(size_t)row*1024 + j] = bl;
        belbf[(size_t)row*1024 + j] = f2b(bl);
      }
  }
}

__device__ __forceinline__ void epi_qp(const f32x4 acc[4][4], const float* bb, const float* noise,
    float* om, float* os, float* ost, int rbase, int nt, int wm, int wn, int fl, int fg) {
  const int cb = nt*128 + wn*64;
#pragma unroll
  for (int gg = 0; gg < 2; ++gg) {
    const int j = nt*64 + (wn*2 + gg)*16 + fl;
    const float bm = bb[cb + gg*32 + fl];
    const float bs = bb[cb + gg*32 + 16 + fl];
#pragma unroll
    for (int mf = 0; mf < 4; ++mf)
#pragma unroll
      for (int r = 0; r < 4; ++r) {
        const int row = rbase + wm*64 + mf*16 + fg*4 + r;
        const float mean = acc[mf][2*gg][r] + bm;
        const float sd = sp_f(acc[mf][2*gg+1][r] + bs) + 0.1f;
        const size_t o = (size_t)row*256 + j;
        om[o] = mean; os[o] = sd; ost[o] = mean + sd*noise[o];
      }
  }
}

struct PP {
  const float *prev_state, *prev_belief, *actions, *obs, *nonterm, *nb, *np, *nq;
  const float *b_sa, *b_eb, *b_ebq, *b_ebp;
  const bf16 *w_sa, *w_gru, *w_eb, *w_bq, *w_ebq, *w_sq, *w_ebp, *w_sp;
  const float *bg, *bbq, *bsq, *bsp;
  bf16 *obs_c, *deter, *bel, *rnn, *sh, *shq, *shp;
  float *o_bel, *o_pst, *o_pm, *o_psd, *o_qst, *o_qm, *o_qsd;
  int *flags;
};

__global__ __launch_bounds__(256) void persist_k(PP p) {
  __shared__ bf16 sA[2][8192];
  __shared__ bf16 sB[2][8192];
  const int bid = blockIdx.x, tid = threadIdx.x;
  const int l = tid & 63, w = tid >> 6;
  const int wm = w >> 1, wn = w & 1, fl = l & 15, fg = l >> 4;
  const int g = bid >> 5, lb = bid & 31, rbase = g << 7;   // 128 rows per group
  int* gfl = p.flags + g * 64;       // group flags (32 used, padded)
  int* ffl = p.flags + 256;          // grid flags (128)
  int evg = 1, evf = 1;

  // ---- prologue: belief carry init + obs_c GEMM (all blocks) ----
#pragma unroll 1
  for (int i = bid*256 + tid; i < 65536; i += GRID*256) {
    float4 a = ((const float4*)p.prev_belief)[i*2];
    float4 b = ((const float4*)p.prev_belief)[i*2 + 1];
    bf16 t8[8] __attribute__((aligned(16)));
    t8[0]=f2b(a.x); t8[1]=f2b(a.y); t8[2]=f2b(a.z); t8[3]=f2b(a.w);
    t8[4]=f2b(b.x); t8[5]=f2b(b.y); t8[6]=f2b(b.z); t8[7]=f2b(b.w);
    ((short8*)p.bel)[i] = *(const short8*)t8;
  }
#pragma unroll 1
  for (int tt = bid; tt < 1024; tt += GRID) {
    const int rb = (tt >> 2) << 7, nt = tt & 3;
    f32x4 acc[4][4] = {};
    kloop_sync_f32(p.obs, 1024, p.w_ebq + 1024, 2048, 1024, rb, nt, acc,
                   tid, w, l, wm, wn, fl, fg, sA[0], sB[0]);
    epi_b16<false,false>(acc, p.obs_c, 512, p.b_ebq, nullptr, 0, rb, nt, wm, wn, fl, fg);
  }
  fence_bar(ffl, GRID, bid, evf); ++evf;

  // ---- 64-step scan: group-local fenced barriers ----
#pragma unroll 1
  for (int t = 0; t < 64; ++t) {
    // S1: deter = relu([q_state*nt | a] @ W_sa' + b_sa)   N=1024 -> 8 tiles
    if (lb < 8) {
      f32x4 acc[4][4] = {};
      const float* ss  = t ? (p.o_qst + (size_t)(t-1)*131072) : p.prev_state;
      const float* ntp = t ? (p.nonterm + (size_t)(t-1)*512) : nullptr;
      kloop_sa(ss, ntp, p.actions + (size_t)t*16384, p.w_sa, rbase, lb, acc,
               tid, w, l, wm, wn, fl, fg, sA[0], sB[0]);
      epi_b16<true,false>(acc, p.deter, 1024, p.b_sa, nullptr, 0, rbase, lb, wm, wn, fl, fg);
    }
    fence_bar(gfl, 32, lb, evg); ++evg;
    // S2: GRU fused GEMM [deter|bel] @ Wgru' -> gates -> rnn   N=4096 -> 32 tiles
    {
      f32x4 acc[4][4] = {};
      kloop_async<true>(p.deter, p.bel, 1024, p.w_gru, 2048, 2048, rbase, lb, acc,
                        w, l, wm, wn, fl, fg, sA[0], sA[1], sB[0], sB[1]);
      epi_gru(acc, p.bg, p.bel, p.rnn, rbase, lb, wm, wn, fl, fg);
    }
    fence_bar(gfl, 32, lb, evg); ++evg;
    // S3: sh = relu(rnn @ W_eb' + b_eb)   N=512 -> 4 tiles
    if (lb < 4) {
      f32x4 acc[4][4] = {};
      kloop_async<false>(p.rnn, nullptr, 1024, p.w_eb, 1024, 1024, rbase, lb, acc,
                         w, l, wm, wn, fl, fg, sA[0], sA[1], sB[0], sB[1]);
      epi_b16<true,false>(acc, p.sh, 512, p.b_eb, nullptr, 0, rbase, lb, wm, wn, fl, fg);
    }
    fence_bar(gfl, 32, lb, evg); ++evg;
    // S4: belief head (paired W_bq')   N=2048 -> 16 tiles
    if (lb < 16) {
      f32x4 acc[4][4] = {};
      kloop_async<false>(p.sh, nullptr, 512, p.w_bq, 512, 512, rbase, lb, acc,
                         w, l, wm, wn, fl, fg, sA[0], sA[1], sB[0], sB[1]);
      epi_bq(acc, p.bbq, p.nb + (size_t)t*524288, p.o_bel + (size_t)t*524288, p.bel,
             rbase, lb, wm, wn, fl, fg);
    }
    fence_bar(gfl, 32, lb, evg); ++evg;
    // S5: shq = relu(bel @ W_ebq'[:, :1024] + obs_c[t])   N=512 -> 4 tiles
    if (lb < 4) {
      f32x4 acc[4][4] = {};
      kloop_async<false>(p.bel, nullptr, 1024, p.w_ebq, 2048, 1024, rbase, lb, acc,
                         w, l, wm, wn, fl, fg, sA[0], sA[1], sB[0], sB[1]);
      epi_b16<true,true>(acc, p.shq, 512, nullptr, p.obs_c + (size_t)t*262144, 512,
                         rbase, lb, wm, wn, fl, fg);
    }
    fence_bar(gfl, 32, lb, evg); ++evg;
    // S6: q head (paired W_sq')   N=512 -> 4 tiles
    if (lb < 4) {
      f32x4 acc[4][4] = {};
      kloop_async<false>(p.shq, nullptr, 512, p.w_sq, 512, 512, rbase, lb, acc,
                         w, l, wm, wn, fl, fg, sA[0], sA[1], sB[0], sB[1]);
      epi_qp(acc, p.bsq, p.nq + (size_t)t*131072,
             p.o_qm + (size_t)t*131072, p.o_qsd + (size_t)t*131072,
             p.o_qst + (size_t)t*131072, rbase, lb, wm, wn, fl, fg);
    }
    fence_bar(gfl, 32, lb, evg); ++evg;
  }

  fence_bar(ffl, GRID, bid, evf); ++evf;   // flush scan outputs (o_bel etc.)

  // ---- prior: shp = relu(beliefs @ W_ebp' + b_ebp) ----
#pragma unroll 1
  for (int tt = bid; tt < 1024; tt += GRID) {
    const int rb = (tt >> 2) << 7, nt = tt & 3;
    f32x4 acc[4][4] = {};
    kloop_sync_f32(p.o_bel, 1024, p.w_ebp, 1024, 1024, rb, nt, acc,
                   tid, w, l, wm, wn, fl, fg, sA[0], sB[0]);
    epi_b16<true,false>(acc, p.shp, 512, p.b_ebp, nullptr, 0, rb, nt, wm, wn, fl, fg);
  }
  fence_bar(ffl, GRID, bid, evf); ++evf;

  // ---- p head: 8 chunks of 4096 rows; fenced barrier between read & overwrite ----
#pragma unroll 1
  for (int c = 0; c < 8; ++c) {
    const int rb = (c*32 + (bid >> 2)) << 7, nt = bid & 3;
    f32x4 acc[4][4] = {};
    kloop_plain(p.shp, 512, p.w_sp, 512, 512, rb, nt, acc,
                w, l, wm, wn, fl, fg, sA[0], sA[1], sB[0], sB[1]);
    fence_bar(ffl, GRID, bid, evf); ++evf;
    epi_qp(acc, p.bsp, p.np, p.o_pm, p.o_psd, p.o_pst, rb, nt, wm, wn, fl, fg);
  }
}

// ---- prep kernels (identical to R2, which passed) ----
__global__ __launch_bounds__(256) void k_cvt8(const float* __restrict__ s, bf16* __restrict__ d, int n8) {
  int i = blockIdx.x*256 + threadIdx.x;
  if (i >= n8) return;
  float4 a = ((const float4*)s)[i*2], b = ((const float4*)s)[i*2+1];
  bf16 t8[8] __attribute__((aligned(16)));
  t8[0]=f2b(a.x); t8[1]=f2b(a.y); t8[2]=f2b(a.z); t8[3]=f2b(a.w);
  t8[4]=f2b(b.x); t8[5]=f2b(b.y); t8[6]=f2b(b.z); t8[7]=f2b(b.w);
  ((short8*)d)[i] = *(const short8*)t8;
}

__global__ __launch_bounds__(256) void k_wsa(const float* __restrict__ W, bf16* __restrict__ dst) {
  int i = blockIdx.x*256 + threadIdx.x;
  if (i >= 40960) return;
  int e = i*8, r = e/320, c = e - r*320;
  bf16 t8[8] __attribute__((aligned(16)));
  if (c < 288) {
    const float* s = W + (size_t)r*288 + c;
    float4 a = ((const float4*)s)[0], b = ((const float4*)s)[1];
    t8[0]=f2b(a.x); t8[1]=f2b(a.y); t8[2]=f2b(a.z); t8[3]=f2b(a.w);
    t8[4]=f2b(b.x); t8[5]=f2b(b.y); t8[6]=f2b(b.z); t8[7]=f2b(b.w);
  } else {
    for (int q = 0; q < 8; ++q) t8[q] = f2b(0.f);
  }
  *(short8*)(dst + e) = *(const short8*)t8;
}

__global__ __launch_bounds__(256) void k_gru_r(const float* __restrict__ Wih, const float* __restrict__ Whh,
                                               bf16* __restrict__ dst) {
  int idx = blockIdx.x*256 + threadIdx.x;
  if (idx >= 2097152) return;
  int rp = idx >> 9;
  int c4 = (idx & 511) << 2;
  int nt = rp >> 7, id = rp & 127;
  int wn2 = (id >> 6) & 1, nf = (id >> 4) & 3, fl2 = id & 15;
  int j = nt*32 + wn2*16 + fl2;
  float4 v = {0,0,0,0};
  if (c4 < 1024) {
    int srow = (nf==0) ? j : (nf==1) ? 1024+j : (nf==2) ? 2048+j : -1;
    if (srow >= 0) v = *(const float4*)(Wih + (size_t)srow*1024 + c4);
  } else {
    int srow = (nf==0) ? j : (nf==1) ? 1024+j : (nf==3) ? 2048+j : -1;
    if (srow >= 0) v = *(const float4*)(Whh + (size_t)srow*1024 + (c4-1024));
  }
  bf16 t4[4] __attribute__((aligned(8)));
  t4[0]=f2b(v.x); t4[1]=f2b(v.y); t4[2]=f2b(v.z); t4[3]=f2b(v.w);
  *(uint2*)(dst + (size_t)rp*2048 + c4) = *(const uint2*)t4;
}

__global__ __launch_bounds__(256) void k_pair(const float* __restrict__ src, bf16* __restrict__ dst,
                                              int halfN, int n) {
  int idx = blockIdx.x*256 + threadIdx.x;
  if (idx >= n) return;
  int rp = idx >> 7;
  int c4 = (idx & 127) << 2;
  int nt = rp >> 7, id = rp & 127;
  int pb = (id >> 5) & 3, comp = (id >> 4) & 1, fl2 = id & 15;
  int j = nt*64 + pb*16 + fl2;
  int srow = comp*halfN + j;
  float4 v = *(const float4*)(src + (size_t)srow*512 + c4);
  bf16 t4[4] __attribute__((aligned(8)));
  t4[0]=f2b(v.x); t4[1]=f2b(v.y); t4[2]=f2b(v.z); t4[3]=f2b(v.w);
  *(uint2*)(dst + (size_t)rp*512 + c4) = *(const uint2*)t4;
}

__global__ __launch_bounds__(256) void k_bias(const float* b_ih, const float* b_hh, const float* b_bq,
                                              const float* b_sq, const float* b_sp,
                                              float* bg, float* bbq, float* bsq, float* bsp) {
  for (int i = threadIdx.x; i < 4096; i += 256) {
    int nt = i >> 7, id = i & 127;
    int wn2 = (id >> 6) & 1, nf = (id >> 4) & 3, fl2 = id & 15;
    int j = nt*32 + wn2*16 + fl2;
    float v;
    if (nf == 0) v = b_ih[j] + b_hh[j];
    else if (nf == 1) v = b_ih[1024+j] + b_hh[1024+j];
    else if (nf == 2) v = b_ih[2048+j];
    else v = b_hh[2048+j];
    bg[i] = v;
  }
  for (int i = threadIdx.x; i < 2048; i += 256) {
    int nt = i >> 7, id = i & 127, pb = (id >> 5) & 3, comp = (id >> 4) & 1, fl2 = id & 15;
    int j = nt*64 + pb*16 + fl2;
    bbq[i] = b_bq[comp*1024 + j];
  }
  for (int i = threadIdx.x; i < 512; i += 256) {
    int nt = i >> 7, id = i & 127, pb = (id >> 5) & 3, comp = (id >> 4) & 1, fl2 = id & 15;
    int j = nt*64 + pb*16 + fl2;
    bsq[i] = b_sq[comp*256 + j];
    bsp[i] = b_sp[comp*256 + j];
  }
}

extern "C" void kernel_launch(void* const* d_in, const int* in_sizes, int n_in,
                              void* d_out, int out_size, void* d_ws, size_t ws_size,
                              hipStream_t stream) {
  const float* prev_state   = (const float*)d_in[0];
  const float* prev_belief  = (const float*)d_in[1];
  const float* actions      = (const float*)d_in[2];
  const float* observations = (const float*)d_in[3];
  const float* nonterm      = (const float*)d_in[4];
  const float* noise_belief = (const float*)d_in[5];
  const float* noise_prior  = (const float*)d_in[6];
  const float* noise_post   = (const float*)d_in[7];
  const float* W_sa  = (const float*)d_in[8];  const float* b_sa  = (const float*)d_in[9];
  const float* W_ih  = (const float*)d_in[10]; const float* b_ih  = (const float*)d_in[11];
  const float* W_hh  = (const float*)d_in[12]; const float* b_hh  = (const float*)d_in[13];
  const float* W_eb  = (const float*)d_in[14]; const float* b_eb  = (const float*)d_in[15];
  const float* W_bq  = (const float*)d_in[16]; const float* b_bq  = (const float*)d_in[17];
  const float* W_ebp = (const float*)d_in[18]; const float* b_ebp = (const float*)d_in[19];
  const float* W_sp  = (const float*)d_in[20]; const float* b_sp  = (const float*)d_in[21];
  const float* W_ebq = (const float*)d_in[22]; const float* b_ebq = (const float*)d_in[23];
  const float* W_sq  = (const float*)d_in[24]; const float* b_sq  = (const float*)d_in[25];

  float* out = (float*)d_out;
  char* ws = (char*)d_ws;

  // ws layout
  int* flags  = (int*)ws;             // [0..255] group flags, [256..383] grid flags
  float* bg   = (float*)(ws + 4096);  // [4096]
  float* bbq  = (float*)(ws + 20480); // [2048]
  float* bsq  = (float*)(ws + 28672); // [512]
  float* bsp  = (float*)(ws + 30720); // [512]
  bf16* wb    = (bf16*)(ws + 32768);
  bf16* w_sa  = wb;                   // [1024][320]
  bf16* w_gru = wb + 327680;          // [4096][2048]
  bf16* w_eb  = wb + 8716288;         // [512][1024]
  bf16* w_bq  = wb + 9240576;         // [2048][512]
  bf16* w_ebq = wb + 10289152;        // [512][2048]
  bf16* w_sq  = wb + 11337728;        // [512][512]
  bf16* w_ebp = wb + 11599872;        // [512][1024]
  bf16* w_sp  = wb + 12124160;        // [512][512]

  // out-region scratch (f32 element offsets)
  float* o_bel = out;
  float* o_pst = out + 33554432;
  float* o_pm  = out + 41943040;
  float* o_psd = out + 50331648;
  float* o_qst = out + 58720256;
  float* o_qm  = out + 67108864;
  float* o_qsd = out + 75497472;
  bf16* obs_c = (bf16*)o_pm;          // [32768][512] bf16 (dead until p_mean written)
  bf16* shp   = (bf16*)o_pst;         // [32768][512] bf16 (overwritten row-staggered)
  bf16* deter = (bf16*)o_psd;         // scan activations in p_std region
  bf16* belb  = deter + 524288;
  bf16* rnn   = belb + 524288;
  bf16* sh    = rnn + 524288;
  bf16* shq   = sh + 262144;

  hipMemsetAsync(ws, 0, 4096, stream);
  k_wsa  <<<160, 256, 0, stream>>>(W_sa, w_sa);
  k_gru_r<<<8192, 256, 0, stream>>>(W_ih, W_hh, w_gru);
  k_cvt8 <<<256, 256, 0, stream>>>(W_eb, w_eb, 65536);
  k_pair <<<1024, 256, 0, stream>>>(W_bq, w_bq, 1024, 262144);
  k_cvt8 <<<512, 256, 0, stream>>>(W_ebq, w_ebq, 131072);
  k_pair <<<256, 256, 0, stream>>>(W_sq, w_sq, 256, 65536);
  k_cvt8 <<<256, 256, 0, stream>>>(W_ebp, w_ebp, 65536);
  k_pair <<<256, 256, 0, stream>>>(W_sp, w_sp, 256, 65536);
  k_bias <<<1, 256, 0, stream>>>(b_ih, b_hh, b_bq, b_sq, b_sp, bg, bbq, bsq, bsp);

  PP p;
  p.prev_state = prev_state; p.prev_belief = prev_belief; p.actions = actions;
  p.obs = observations; p.nonterm = nonterm; p.nb = noise_belief; p.np = noise_prior; p.nq = noise_post;
  p.b_sa = b_sa; p.b_eb = b_eb; p.b_ebq = b_ebq; p.b_ebp = b_ebp;
  p.w_sa = w_sa; p.w_gru = w_gru; p.w_eb = w_eb; p.w_bq = w_bq;
  p.w_ebq = w_ebq; p.w_sq = w_sq; p.w_ebp = w_ebp; p.w_sp = w_sp;
  p.bg = bg; p.bbq = bbq; p.bsq = bsq; p.bsp = bsp;
  p.obs_c = obs_c; p.deter = deter; p.bel = belb; p.rnn = rnn; p.sh = sh; p.shq = shq; p.shp = shp;
  p.o_bel = o_bel; p.o_pst = o_pst; p.o_pm = o_pm; p.o_psd = o_psd;
  p.o_qst = o_qst; p.o_qm = o_qm; p.o_qsd = o_qsd;
  p.flags = flags;

  persist_k<<<GRID, 256, 0, stream>>>(p);
}

// Round 7
// 18610.838 us; speedup vs baseline: 1.5928x; 1.0184x over previous
//
#include <hip/hip_runtime.h>
#include <hip/hip_bf16.h>
#include <math.h>

// RSSM scan, MI355X. ZERO-SYNC design: 32 blocks x 16 batch rows, each block
// carries its rows through all 64 steps with intermediates in LDS. No grid
// barriers, no fences, no cross-block traffic. Weights pre-packed into
// MFMA-fragment order -> B loads are perfectly coalesced dwordx4, no LDS
// staging. Prologue/prior/p-head are separate wide-grid kernels.
// D=1024 Z=256 A=32 H=512 E=1024, T=64, B=512.

using bf16 = __hip_bfloat16;
using short8 = __attribute__((ext_vector_type(8))) short;
using f32x4 = __attribute__((ext_vector_type(4))) float;

__device__ __forceinline__ float sp_f(float x){ return x > 15.f ? x : log1pf(__expf(x)); }
__device__ __forceinline__ float sg_f(float x){ return 1.f/(1.f+__expf(-x)); }
__device__ __forceinline__ float b2f(bf16 x){ return __bfloat162float(x); }
__device__ __forceinline__ bf16  f2b(float x){ return __float2bfloat16(x); }

// ===== A-LDS swizzled layout (elem index): conflict-free MFMA A-frag reads
__device__ __forceinline__ int aoff(int r, int c, int ldk) {
  return r*ldk + (c & ~63) + ((((c>>3)&7) ^ (r&7))<<3) + (c&7);
}

// ===== 4-fragment GEMM group: acc[q] over K, A from LDS reader, B packed
template<int KC, typename AR>
__device__ __forceinline__ void gemm4(f32x4 acc[4], const bf16* __restrict__ wpf,
                                      int lane, AR aread) {
#pragma unroll 2
  for (int kc = 0; kc < KC; ++kc) {
    short8 a = aread(kc*32);
#pragma unroll
    for (int q = 0; q < 4; ++q) {
      short8 b = *(const short8*)(wpf + ((size_t)q*KC + kc)*512 + lane*8);
      asm("v_mfma_f32_16x16x32_bf16 %0, %1, %2, %0" : "+v"(acc[q]) : "v"(a), "v"(b));
    }
  }
}

struct SP {
  const float *prev_state, *prev_belief, *actions, *nonterm, *nb, *nq;
  const bf16 *w_sa, *w_gru, *w_eb, *w_bq, *w_ebq, *w_sq;
  const float *bg, *b_sa, *b_eb, *b_bq, *b_sq;
  const bf16 *obs_c;
  float *o_bel, *o_qst, *o_qm, *o_qsd;
};

__global__ __launch_bounds__(256) void scan_k(SP p) {
  __shared__ bf16 sB[16*1024];   // bel carry
  __shared__ bf16 sD[16*1024];   // deter; after GRU: sh (cols 0-511) + shq (512-1023)
  __shared__ bf16 sR[16*1024];   // rnn; after eb: qsa [16][320]
  const int tid = threadIdx.x, l = tid & 63, w = tid >> 6;
  const int fl = l & 15, fg = l >> 4;
  const int rbase = blockIdx.x * 16;

  // ---- prologue: bel <- prev_belief ; qsa <- prev_state (no nt at t=0) ----
  {
    const int r = tid >> 4;
    const int c0 = (tid & 15) * 64;
    const float* src = p.prev_belief + (size_t)(rbase + r)*1024 + c0;
#pragma unroll
    for (int s = 0; s < 8; ++s) {
      float4 a = *(const float4*)(src + s*8);
      float4 b = *(const float4*)(src + s*8 + 4);
      bf16 t8[8] __attribute__((aligned(16)));
      t8[0]=f2b(a.x); t8[1]=f2b(a.y); t8[2]=f2b(a.z); t8[3]=f2b(a.w);
      t8[4]=f2b(b.x); t8[5]=f2b(b.y); t8[6]=f2b(b.z); t8[7]=f2b(b.w);
      *(short8*)(sB + aoff(r, c0 + s*8, 1024)) = *(const short8*)t8;
    }
    const int c1 = (tid & 15) * 16;
    const float* sq2 = p.prev_state + (size_t)(rbase + r)*256 + c1;
#pragma unroll
    for (int s = 0; s < 2; ++s) {
      float4 a = *(const float4*)(sq2 + s*8);
      float4 b = *(const float4*)(sq2 + s*8 + 4);
      bf16 t8[8] __attribute__((aligned(16)));
      t8[0]=f2b(a.x); t8[1]=f2b(a.y); t8[2]=f2b(a.z); t8[3]=f2b(a.w);
      t8[4]=f2b(b.x); t8[5]=f2b(b.y); t8[6]=f2b(b.z); t8[7]=f2b(b.w);
      *(short8*)(sR + aoff(r, c1 + s*8, 320)) = *(const short8*)t8;
    }
  }
  __syncthreads();

#pragma unroll 1
  for (int t = 0; t < 64; ++t) {
    // ---- S1 prep: actions -> qsa cols 256..287, zeros 288..319 ----
    if (tid < 128) {
      const int r = tid >> 3, cc = (tid & 7) * 4;
      float4 a = *(const float4*)(p.actions + (size_t)(t*512 + rbase + r)*32 + cc);
      sR[aoff(r, 256+cc,   320)] = f2b(a.x);
      sR[aoff(r, 256+cc+1, 320)] = f2b(a.y);
      sR[aoff(r, 256+cc+2, 320)] = f2b(a.z);
      sR[aoff(r, 256+cc+3, 320)] = f2b(a.w);
    } else if (tid < 192) {
      const int r = (tid-128) >> 2, c0 = 288 + ((tid-128)&3)*8;
      bf16 z8[8] __attribute__((aligned(16))) = {};
      *(short8*)(sR + aoff(r, c0, 320)) = *(const short8*)z8;
    }
    __syncthreads();
    // ---- S1: deter = relu(qsa @ Wsa' + b_sa), N=1024 ----
    {
      auto aq = [&](int c){ return *(const short8*)(sR + aoff(fl, c + fg*8, 320)); };
#pragma unroll 1
      for (int g = 0; g < 4; ++g) {
        f32x4 acc[4] = {};
        const int f0 = w*16 + g*4;
        gemm4<10>(acc, p.w_sa + (size_t)f0*10*512, l, aq);
#pragma unroll
        for (int q = 0; q < 4; ++q) {
          const int col = (f0+q)*16 + fl;
          const float bv = p.b_sa[col];
#pragma unroll
          for (int rr = 0; rr < 4; ++rr) {
            float v = acc[q][rr] + bv;
            sD[aoff(fg*4+rr, col, 1024)] = f2b(v > 0.f ? v : 0.f);
          }
        }
      }
    }
    __syncthreads();
    // ---- S2: GRU [deter|bel] @ Wgru' -> gates -> rnn, N=1024 x 4 gates ----
    {
#pragma unroll 1
      for (int g = 0; g < 4; ++g) {
        f32x4 acc[4][4] = {};   // [jtq][gate]
#pragma unroll 1
        for (int kc = 0; kc < 64; ++kc) {
          const int c = kc*32 + fg*8;
          short8 a = (c < 1024) ? *(const short8*)(sD + aoff(fl, c, 1024))
                                : *(const short8*)(sB + aoff(fl, c - 1024, 1024));
#pragma unroll
          for (int jq = 0; jq < 4; ++jq) {
            const int jt = w*16 + g*4 + jq;
#pragma unroll
            for (int nf = 0; nf < 4; ++nf) {
              short8 b = *(const short8*)(p.w_gru + ((size_t)(jt*4+nf)*64 + kc)*512 + l*8);
              asm("v_mfma_f32_16x16x32_bf16 %0, %1, %2, %0"
                  : "+v"(acc[jq][nf]) : "v"(a), "v"(b));
            }
          }
        }
#pragma unroll
        for (int jq = 0; jq < 4; ++jq) {
          const int j = (w*16 + g*4 + jq)*16 + fl;
          const float b0 = p.bg[j], b1 = p.bg[1024+j], b2 = p.bg[2048+j], b3 = p.bg[3072+j];
#pragma unroll
          for (int rr = 0; rr < 4; ++rr) {
            const int row = fg*4 + rr;
            const float a0 = acc[jq][0][rr] + b0;
            const float a1 = acc[jq][1][rr] + b1;
            const float a2 = acc[jq][2][rr] + b2;
            const float a3 = acc[jq][3][rr] + b3;
            const float r_ = sg_f(a0), z_ = sg_f(a1);
            const float nn = tanhf(a2 + r_*a3);
            const float h = b2f(sB[aoff(row, j, 1024)]);
            sR[aoff(row, j, 1024)] = f2b((1.f - z_)*nn + z_*h);
          }
        }
      }
    }
    __syncthreads();
    // ---- S3: sh = relu(rnn @ Web' + b_eb), N=512 -> sD cols 0..511 ----
    {
      auto ar = [&](int c){ return *(const short8*)(sR + aoff(fl, c + fg*8, 1024)); };
#pragma unroll 1
      for (int g = 0; g < 2; ++g) {
        f32x4 acc[4] = {};
        const int f0 = w*8 + g*4;
        gemm4<32>(acc, p.w_eb + (size_t)f0*32*512, l, ar);
#pragma unroll
        for (int q = 0; q < 4; ++q) {
          const int col = (f0+q)*16 + fl;
          const float bv = p.b_eb[col];
#pragma unroll
          for (int rr = 0; rr < 4; ++rr) {
            float v = acc[q][rr] + bv;
            sD[aoff(fg*4+rr, col, 1024)] = f2b(v > 0.f ? v : 0.f);
          }
        }
      }
    }
    __syncthreads();
    // ---- S4: belief head (paired Wbq'): bel = mean + (sp(std)+0.1)*noise ----
    {
      auto as = [&](int c){ return *(const short8*)(sD + aoff(fl, c + fg*8, 1024)); };
      const float* nbt = p.nb + (size_t)(t*512 + rbase)*1024;
      float* obt = p.o_bel + (size_t)(t*512 + rbase)*1024;
#pragma unroll 1
      for (int g = 0; g < 8; ++g) {
        f32x4 acc[4] = {};
        const int f0 = w*32 + g*4;   // frags: (jt, mean/std) pairs, jt = w*16+g*2
        gemm4<16>(acc, p.w_bq + (size_t)f0*16*512, l, as);
#pragma unroll
        for (int jj = 0; jj < 2; ++jj) {
          const int j = (w*16 + g*2 + jj)*16 + fl;
          const float bm = p.b_bq[j], bs = p.b_bq[1024 + j];
#pragma unroll
          for (int rr = 0; rr < 4; ++rr) {
            const int row = fg*4 + rr;
            const float mean = acc[2*jj][rr] + bm;
            const float sd = sp_f(acc[2*jj+1][rr] + bs) + 0.1f;
            const float bl = mean + sd * nbt[(size_t)row*1024 + j];
            obt[(size_t)row*1024 + j] = bl;
            sB[aoff(row, j, 1024)] = f2b(bl);
          }
        }
      }
    }
    __syncthreads();
    // ---- S5: shq = relu(bel @ Webq_lo' + obs_c[t]), N=512 -> sD cols 512.. ----
    {
      auto ab = [&](int c){ return *(const short8*)(sB + aoff(fl, c + fg*8, 1024)); };
      const bf16* oc = p.obs_c + (size_t)(t*512 + rbase)*512;
#pragma unroll 1
      for (int g = 0; g < 2; ++g) {
        f32x4 acc[4] = {};
        const int f0 = w*8 + g*4;
        gemm4<32>(acc, p.w_ebq + (size_t)f0*32*512, l, ab);
#pragma unroll
        for (int q = 0; q < 4; ++q) {
          const int col = (f0+q)*16 + fl;
#pragma unroll
          for (int rr = 0; rr < 4; ++rr) {
            const int row = fg*4 + rr;
            float v = acc[q][rr] + b2f(oc[(size_t)row*512 + col]);
            sD[aoff(row, 512 + col, 1024)] = f2b(v > 0.f ? v : 0.f);
          }
        }
      }
    }
    __syncthreads();
    // ---- S6: q head (paired Wsq') -> outputs + qsa for next step ----
    {
      auto ax = [&](int c){ return *(const short8*)(sD + aoff(fl, 512 + c + fg*8, 1024)); };
      const float* nqt = p.nq + (size_t)(t*512 + rbase)*256;
      float* qm = p.o_qm  + (size_t)(t*512 + rbase)*256;
      float* qs = p.o_qsd + (size_t)(t*512 + rbase)*256;
      float* qt = p.o_qst + (size_t)(t*512 + rbase)*256;
      const float* ntp = p.nonterm + (size_t)t*512 + rbase;
#pragma unroll 1
      for (int g = 0; g < 2; ++g) {
        f32x4 acc[4] = {};
        const int f0 = w*8 + g*4;    // jt = w*4 + g*2
        gemm4<16>(acc, p.w_sq + (size_t)f0*16*512, l, ax);
#pragma unroll
        for (int jj = 0; jj < 2; ++jj) {
          const int j = (w*4 + g*2 + jj)*16 + fl;
          const float bm = p.b_sq[j], bs = p.b_sq[256 + j];
#pragma unroll
          for (int rr = 0; rr < 4; ++rr) {
            const int row = fg*4 + rr;
            const float mean = acc[2*jj][rr] + bm;
            const float sd = sp_f(acc[2*jj+1][rr] + bs) + 0.1f;
            const float q = mean + sd * nqt[(size_t)row*256 + j];
            qm[(size_t)row*256 + j] = mean;
            qs[(size_t)row*256 + j] = sd;
            qt[(size_t)row*256 + j] = q;
            sR[aoff(row, j, 320)] = f2b(q * ntp[row]);
          }
        }
      }
    }
    __syncthreads();
  }
}

// ===== wide-kernel helpers (R6-proven: lds_off / glds_tile / mfma_tiles) =====
__device__ __forceinline__ int lds_off(int row, int slot){ return row*64 + ((slot ^ (row & 7)) << 3); }

__device__ __forceinline__ void glds_tile(const bf16* base, int ld, bf16* buf, int w, int l) {
  const int rsub = l >> 3;
  const int slot = (l & 7) ^ rsub;
  const bf16* src = base + (size_t)(w*32 + rsub)*ld + slot*8;
#pragma unroll
  for (int i = 0; i < 4; ++i)
    __builtin_amdgcn_global_load_lds((const __attribute__((address_space(1))) void*)(src + (size_t)(i*8)*ld),
                                     (__attribute__((address_space(3))) void*)(buf + (w*32 + i*8)*64),
                                     16, 0, 0);
}
__device__ __forceinline__ void glds_tile64(const bf16* base, int ld, bf16* buf, int w, int l) {
  const int rsub = l >> 3;
  const int slot = (l & 7) ^ rsub;
  const bf16* src = base + (size_t)(w*16 + rsub)*ld + slot*8;
#pragma unroll
  for (int i = 0; i < 2; ++i)
    __builtin_amdgcn_global_load_lds((const __attribute__((address_space(1))) void*)(src + (size_t)(i*8)*ld),
                                     (__attribute__((address_space(3))) void*)(buf + (w*16 + i*8)*64),
                                     16, 0, 0);
}

__device__ __forceinline__ void mfma_tiles(f32x4 acc[4][4], const bf16* bA, const bf16* bB,
                                           int wm, int wn, int fl, int fg) {
#pragma unroll
  for (int ks = 0; ks < 2; ++ks) {
    short8 af[4], bfr[4];
#pragma unroll
    for (int i = 0; i < 4; ++i)
      af[i] = *(const short8*)(bA + lds_off(wm*64 + i*16 + fl, ks*4 + fg));
#pragma unroll
    for (int i = 0; i < 4; ++i)
      bfr[i] = *(const short8*)(bB + lds_off(wn*64 + i*16 + fl, ks*4 + fg));
#pragma unroll
    for (int mf = 0; mf < 4; ++mf)
#pragma unroll
      for (int nf = 0; nf < 4; ++nf)
        asm("v_mfma_f32_16x16x32_bf16 %0, %1, %2, %0"
            : "+v"(acc[mf][nf]) : "v"(af[mf]), "v"(bfr[nf]));
  }
}

// f32-A 128-row GEMM tile kernel body (obs_c / shp), R6-proven structure
template<bool RELU>
__device__ void wide_f32_gemm(const float* A, int lda, const bf16* Bw, int ldb, int K,
                              const float* bias, bf16* dst, int ldc) {
  __shared__ bf16 sA0[8192];
  __shared__ bf16 sB0[8192];
  const int tid = threadIdx.x, l = tid & 63, w = tid >> 6;
  const int wm = w >> 1, wn = w & 1, fl = l & 15, fg = l >> 4;
  const int rb = ((int)blockIdx.x >> 2) << 7, nt = blockIdx.x & 3;
  f32x4 acc[4][4] = {};
#pragma unroll 1
  for (int ki = 0; ki < (K >> 6); ++ki) {
    const int k0 = ki << 6;
    glds_tile(Bw + (size_t)(nt*128)*ldb + k0, ldb, sB0, w, l);
#pragma unroll
    for (int i = 0; i < 4; ++i) {
      const int sid = tid + (i << 8);
      const int row = sid >> 3, s = sid & 7;
      const float* src = A + (size_t)(rb + row)*lda + k0 + s*8;
      float4 a = ((const float4*)src)[0], b = ((const float4*)src)[1];
      bf16 t8[8] __attribute__((aligned(16)));
      t8[0]=f2b(a.x); t8[1]=f2b(a.y); t8[2]=f2b(a.z); t8[3]=f2b(a.w);
      t8[4]=f2b(b.x); t8[5]=f2b(b.y); t8[6]=f2b(b.z); t8[7]=f2b(b.w);
      *(short8*)(sA0 + lds_off(row, s)) = *(const short8*)t8;
    }
    asm volatile("s_waitcnt vmcnt(0) lgkmcnt(0)" ::: "memory");
    __builtin_amdgcn_s_barrier();
    mfma_tiles(acc, sA0, sB0, wm, wn, fl, fg);
    __builtin_amdgcn_s_barrier();
  }
#pragma unroll
  for (int mf = 0; mf < 4; ++mf)
#pragma unroll
    for (int nf = 0; nf < 4; ++nf) {
      const int col = nt*128 + wn*64 + nf*16 + fl;
      const float bv = bias[col];
#pragma unroll
      for (int r = 0; r < 4; ++r) {
        const int row = rb + wm*64 + mf*16 + fg*4 + r;
        float v = acc[mf][nf][r] + bv;
        if (RELU) v = v > 0.f ? v : 0.f;
        dst[(size_t)row*ldc + col] = f2b(v);
      }
    }
}

__global__ __launch_bounds__(256) void obsc_k(const float* obs, const bf16* webqh,
                                              const float* b_ebq, bf16* obs_c) {
  wide_f32_gemm<false>(obs, 1024, webqh, 1024, 1024, b_ebq, obs_c, 512);
}
__global__ __launch_bounds__(256) void shp_k(const float* bel, const bf16* webp,
                                             const float* b_ebp, bf16* shp) {
  wide_f32_gemm<true>(bel, 1024, webp, 1024, 1024, b_ebp, shp, 512);
}

// p-head: row-local 64-row blocks; stash p_state in LDS (aliases shp bytes)
__global__ __launch_bounds__(256) void phead_k(const bf16* shp, const bf16* wsp,
    const float* b_sp, const float* np, float* o_pm, float* o_psd, float* o_pst) {
  __shared__ bf16 stA[64*64];
  __shared__ bf16 stB[128*64];
  __shared__ float stash[64*256];
  const int tid = threadIdx.x, l = tid & 63, w = tid >> 6;
  const int wm = w >> 1, wn = w & 1, fl = l & 15, fg = l >> 4;
  const int R0 = blockIdx.x * 64;
#pragma unroll 1
  for (int nt = 0; nt < 4; ++nt) {
    f32x4 acc[2][4] = {};
#pragma unroll 1
    for (int kc = 0; kc < 8; ++kc) {
      glds_tile64(shp + (size_t)R0*512 + kc*64, 512, stA, w, l);
      glds_tile(wsp + (size_t)(nt*128)*512 + kc*64, 512, stB, w, l);
      asm volatile("s_waitcnt vmcnt(0)" ::: "memory");
      __builtin_amdgcn_s_barrier();
#pragma unroll
      for (int ks = 0; ks < 2; ++ks) {
        short8 af[2], bfr[4];
#pragma unroll
        for (int mf = 0; mf < 2; ++mf)
          af[mf] = *(const short8*)(stA + lds_off(wm*32 + mf*16 + fl, ks*4 + fg));
#pragma unroll
        for (int nf = 0; nf < 4; ++nf)
          bfr[nf] = *(const short8*)(stB + lds_off(wn*64 + nf*16 + fl, ks*4 + fg));
#pragma unroll
        for (int mf = 0; mf < 2; ++mf)
#pragma unroll
          for (int nf = 0; nf < 4; ++nf)
            asm("v_mfma_f32_16x16x32_bf16 %0, %1, %2, %0"
                : "+v"(acc[mf][nf]) : "v"(af[mf]), "v"(bfr[nf]));
      }
      __builtin_amdgcn_s_barrier();
    }
#pragma unroll
    for (int mf = 0; mf < 2; ++mf)
#pragma unroll
      for (int gg = 0; gg < 2; ++gg) {
        const int j = nt*64 + (wn*2 + gg)*16 + fl;
        const float bm = b_sp[j], bs = b_sp[256 + j];
#pragma unroll
        for (int rr = 0; rr < 4; ++rr) {
          const int rl = wm*32 + mf*16 + fg*4 + rr;
          const float mean = acc[mf][2*gg][rr] + bm;
          const float sd = sp_f(acc[mf][2*gg+1][rr] + bs) + 0.1f;
          o_pm [(size_t)(R0+rl)*256 + j] = mean;
          o_psd[(size_t)(R0+rl)*256 + j] = sd;
          stash[rl*256 + j] = mean + sd * np[(size_t)(R0+rl)*256 + j];
        }
      }
  }
  __syncthreads();
#pragma unroll 1
  for (int i = tid; i < 4096; i += 256) {
    const int r = i >> 6, c4 = (i & 63) << 2;
    *(float4*)(o_pst + (size_t)(R0+r)*256 + c4) = *(const float4*)(stash + r*256 + c4);
  }
}

// ===== prep: fragment-packing kernels =====
// plain/pair pack: frag fi covers 16 output cols; unit = (fi, kc, lane) -> 8 elems
__global__ __launch_bounds__(256) void k_pack(const float* __restrict__ src, bf16* __restrict__ dst,
    int NF, int KC, int Ksrc, int ldsrc, int rowoff, int pair, int halfN) {
  const int idx = blockIdx.x*256 + threadIdx.x;
  if (idx >= NF*KC*64) return;
  const int lane = idx & 63, kc = (idx >> 6) % KC, fi = idx / (64*KC);
  int col;
  if (pair) { const int jt = fi >> 1, pp = fi & 1; col = pp*halfN + jt*16 + (lane & 15); }
  else col = fi*16 + (lane & 15);
  const int kb = kc*32 + (lane >> 4)*8;
  bf16 t8[8] __attribute__((aligned(16)));
#pragma unroll
  for (int e = 0; e < 8; ++e) {
    const int k = kb + e;
    t8[e] = f2b(k < Ksrc ? src[(size_t)col*ldsrc + rowoff + k] : 0.f);
  }
  *(short8*)(dst + (size_t)idx*8) = *(const short8*)t8;
}

// GRU pack: fi = jt*4 + gate; K-concat [Wih | Whh] with gate row mapping
__global__ __launch_bounds__(256) void k_gru_pack(const float* __restrict__ Wih,
    const float* __restrict__ Whh, bf16* __restrict__ dst) {
  const int idx = blockIdx.x*256 + threadIdx.x;
  if (idx >= 256*64*64) return;
  const int lane = idx & 63, kc = (idx >> 6) & 63, fi = idx >> 12;
  const int jt = fi >> 2, nf = fi & 3;
  const int j = jt*16 + (lane & 15);
  const int kb = kc*32 + (lane >> 4)*8;
  bf16 t8[8] __attribute__((aligned(16)));
#pragma unroll
  for (int e = 0; e < 8; ++e) {
    const int k = kb + e;
    float v = 0.f;
    if (k < 1024) {
      if (nf == 0) v = Wih[(size_t)j*1024 + k];
      else if (nf == 1) v = Wih[(size_t)(1024+j)*1024 + k];
      else if (nf == 2) v = Wih[(size_t)(2048+j)*1024 + k];
    } else {
      const int kk = k - 1024;
      if (nf == 0) v = Whh[(size_t)j*1024 + kk];
      else if (nf == 1) v = Whh[(size_t)(1024+j)*1024 + kk];
      else if (nf == 3) v = Whh[(size_t)(2048+j)*1024 + kk];
    }
    t8[e] = f2b(v);
  }
  *(short8*)(dst + (size_t)idx*8) = *(const short8*)t8;
}

// old-layout converters for the wide kernels
__global__ __launch_bounds__(256) void k_cvt8(const float* __restrict__ s, bf16* __restrict__ d, int n8) {
  const int i = blockIdx.x*256 + threadIdx.x;
  if (i >= n8) return;
  float4 a = ((const float4*)s)[i*2], b = ((const float4*)s)[i*2+1];
  bf16 t8[8] __attribute__((aligned(16)));
  t8[0]=f2b(a.x); t8[1]=f2b(a.y); t8[2]=f2b(a.z); t8[3]=f2b(a.w);
  t8[4]=f2b(b.x); t8[5]=f2b(b.y); t8[6]=f2b(b.z); t8[7]=f2b(b.w);
  ((short8*)d)[i] = *(const short8*)t8;
}
__global__ __launch_bounds__(256) void k_cvthalf(const float* __restrict__ s, bf16* __restrict__ d) {
  const int i = blockIdx.x*256 + threadIdx.x;   // [512][1024] from src ld 2048 off 1024
  if (i >= 65536) return;
  const int r = i >> 7, c8 = (i & 127)*8;
  const float* sp2 = s + (size_t)r*2048 + 1024 + c8;
  float4 a = ((const float4*)sp2)[0], b = ((const float4*)sp2)[1];
  bf16 t8[8] __attribute__((aligned(16)));
  t8[0]=f2b(a.x); t8[1]=f2b(a.y); t8[2]=f2b(a.z); t8[3]=f2b(a.w);
  t8[4]=f2b(b.x); t8[5]=f2b(b.y); t8[6]=f2b(b.z); t8[7]=f2b(b.w);
  *(short8*)(d + (size_t)i*8) = *(const short8*)t8;
}
__global__ __launch_bounds__(256) void k_pair(const float* __restrict__ src, bf16* __restrict__ dst,
                                              int halfN, int n) {
  const int idx = blockIdx.x*256 + threadIdx.x;
  if (idx >= n) return;
  const int rp = idx >> 7;
  const int c4 = (idx & 127) << 2;
  const int nt = rp >> 7, id = rp & 127;
  const int pb = (id >> 5) & 3, comp = (id >> 4) & 1, fl2 = id & 15;
  const int j = nt*64 + pb*16 + fl2;
  const int srow = comp*halfN + j;
  float4 v = *(const float4*)(src + (size_t)srow*512 + c4);
  bf16 t4[4] __attribute__((aligned(8)));
  t4[0]=f2b(v.x); t4[1]=f2b(v.y); t4[2]=f2b(v.z); t4[3]=f2b(v.w);
  *(uint2*)(dst + (size_t)rp*512 + c4) = *(const uint2*)t4;
}
__global__ __launch_bounds__(256) void k_bg(const float* b_ih, const float* b_hh, float* bg) {
  const int i = blockIdx.x*256 + threadIdx.x;
  if (i >= 4096) return;
  const int g = i >> 10, j = i & 1023;
  float v;
  if (g == 0) v = b_ih[j] + b_hh[j];
  else if (g == 1) v = b_ih[1024+j] + b_hh[1024+j];
  else if (g == 2) v = b_ih[2048+j];
  else v = b_hh[2048+j];
  bg[i] = v;
}

extern "C" void kernel_launch(void* const* d_in, const int* in_sizes, int n_in,
                              void* d_out, int out_size, void* d_ws, size_t ws_size,
                              hipStream_t stream) {
  const float* prev_state   = (const float*)d_in[0];
  const float* prev_belief  = (const float*)d_in[1];
  const float* actions      = (const float*)d_in[2];
  const float* observations = (const float*)d_in[3];
  const float* nonterm      = (const float*)d_in[4];
  const float* noise_belief = (const float*)d_in[5];
  const float* noise_prior  = (const float*)d_in[6];
  const float* noise_post   = (const float*)d_in[7];
  const float* W_sa  = (const float*)d_in[8];  const float* b_sa  = (const float*)d_in[9];
  const float* W_ih  = (const float*)d_in[10]; const float* b_ih  = (const float*)d_in[11];
  const float* W_hh  = (const float*)d_in[12]; const float* b_hh  = (const float*)d_in[13];
  const float* W_eb  = (const float*)d_in[14]; const float* b_eb  = (const float*)d_in[15];
  const float* W_bq  = (const float*)d_in[16]; const float* b_bq  = (const float*)d_in[17];
  const float* W_ebp = (const float*)d_in[18]; const float* b_ebp = (const float*)d_in[19];
  const float* W_sp  = (const float*)d_in[20]; const float* b_sp  = (const float*)d_in[21];
  const float* W_ebq = (const float*)d_in[22]; const float* b_ebq = (const float*)d_in[23];
  const float* W_sq  = (const float*)d_in[24]; const float* b_sq  = (const float*)d_in[25];

  float* out = (float*)d_out;
  char* ws = (char*)d_ws;

  // ws layout (24.8 MB, same footprint as proven rounds)
  float* bg   = (float*)ws;                  // [4096] f32
  bf16* wb    = (bf16*)(ws + 16384);
  bf16* w_sa  = wb;                          // packed: 64f x 10kc  = 327,680 elems
  bf16* w_gru = wb + 327680;                 // packed: 256f x 64kc = 8,388,608
  bf16* w_eb  = wb + 8716288;                // packed: 32f x 32kc  = 524,288
  bf16* w_bq  = wb + 9240576;                // packed: 128f x 16kc = 1,048,576
  bf16* w_ebq = wb + 10289152;               // packed: 32f x 32kc  = 524,288
  bf16* w_sq  = wb + 10813440;               // packed: 32f x 16kc  = 262,144
  bf16* w_ebqh= wb + 11075584;               // old [512][1024]     = 524,288
  bf16* w_ebp = wb + 11599872;               // old [512][1024]     = 524,288
  bf16* w_sp  = wb + 12124160;               // old-pair [512][512] = 262,144

  // out-region pointers (f32 elem offsets)
  float* o_bel = out;
  float* o_pst = out + 33554432;
  float* o_pm  = out + 41943040;
  float* o_psd = out + 50331648;
  float* o_qst = out + 58720256;
  float* o_qm  = out + 67108864;
  float* o_qsd = out + 75497472;
  bf16* obs_c = (bf16*)o_pm;    // [32768][512] bf16 (dead until p_mean written)
  bf16* shp   = (bf16*)o_pst;   // [32768][512] bf16 (overwritten row-locally by phead)

  // ---- prep ----
  k_bg      <<<16,   256, 0, stream>>>(b_ih, b_hh, bg);
  k_pack    <<<160,  256, 0, stream>>>(W_sa, w_sa, 64, 10, 288, 288, 0, 0, 0);
  k_gru_pack<<<4096, 256, 0, stream>>>(W_ih, W_hh, w_gru);
  k_pack    <<<256,  256, 0, stream>>>(W_eb, w_eb, 32, 32, 1024, 1024, 0, 0, 0);
  k_pack    <<<512,  256, 0, stream>>>(W_bq, w_bq, 128, 16, 512, 512, 0, 1, 1024);
  k_pack    <<<256,  256, 0, stream>>>(W_ebq, w_ebq, 32, 32, 1024, 2048, 0, 0, 0);
  k_pack    <<<128,  256, 0, stream>>>(W_sq, w_sq, 32, 16, 512, 512, 0, 1, 256);
  k_cvthalf <<<256,  256, 0, stream>>>(W_ebq, w_ebqh);
  k_cvt8    <<<256,  256, 0, stream>>>(W_ebp, w_ebp, 65536);
  k_pair    <<<256,  256, 0, stream>>>(W_sp, w_sp, 256, 65536);

  // ---- prologue: obs contribution (wide) ----
  obsc_k<<<1024, 256, 0, stream>>>(observations, w_ebqh, b_ebq, obs_c);

  // ---- scan: 32 zero-sync row-local blocks ----
  SP p;
  p.prev_state = prev_state; p.prev_belief = prev_belief; p.actions = actions;
  p.nonterm = nonterm; p.nb = noise_belief; p.nq = noise_post;
  p.w_sa = w_sa; p.w_gru = w_gru; p.w_eb = w_eb; p.w_bq = w_bq; p.w_ebq = w_ebq; p.w_sq = w_sq;
  p.bg = bg; p.b_sa = b_sa; p.b_eb = b_eb; p.b_bq = b_bq; p.b_sq = b_sq;
  p.obs_c = obs_c;
  p.o_bel = o_bel; p.o_qst = o_qst; p.o_qm = o_qm; p.o_qsd = o_qsd;
  scan_k<<<32, 256, 0, stream>>>(p);

  // ---- prior branch (wide) ----
  shp_k  <<<1024, 256, 0, stream>>>(o_bel, w_ebp, b_ebp, shp);
  phead_k<<<512,  256, 0, stream>>>(shp, w_sp, b_sp, noise_prior, o_pm, o_psd, o_pst);
}

// Round 8
// 12008.183 us; speedup vs baseline: 2.4686x; 1.5498x over previous
//
#include <hip/hip_runtime.h>
#include <hip/hip_bf16.h>
#include <math.h>

// RSSM scan, MI355X. ZERO-SYNC (R7-proven) + R8: 512-thread scan blocks
// (8 waves, 2x MLP), GRU weights packed with NO zero-pad (17.8MB/step vs
// 22.2), hand-pipelined GRU B-prefetch (ping-pong register buffers).
// 32 blocks x 16 batch rows, intermediates in LDS, no barriers/fences.
// D=1024 Z=256 A=32 H=512 E=1024, T=64, B=512.

using bf16 = __hip_bfloat16;
using short8 = __attribute__((ext_vector_type(8))) short;
using f32x4 = __attribute__((ext_vector_type(4))) float;

__device__ __forceinline__ float sp_f(float x){ return x > 15.f ? x : log1pf(__expf(x)); }
__device__ __forceinline__ float sg_f(float x){ return 1.f/(1.f+__expf(-x)); }
__device__ __forceinline__ float b2f(bf16 x){ return __bfloat162float(x); }
__device__ __forceinline__ bf16  f2b(float x){ return __float2bfloat16(x); }

// A-LDS swizzled layout (elem index): conflict-reduced MFMA A-frag reads
__device__ __forceinline__ int aoff(int r, int c, int ldk) {
  return r*ldk + (c & ~63) + ((((c>>3)&7) ^ (r&7))<<3) + (c&7);
}

// N-frag GEMM group: acc[q] over KC k-chunks; A via lambda, B fragment-packed
template<int KC, typename AR>
__device__ __forceinline__ void gemm4(f32x4 acc[4], const bf16* __restrict__ wpf,
                                      int lane, AR aread) {
#pragma unroll 2
  for (int kc = 0; kc < KC; ++kc) {
    short8 a = aread(kc*32);
#pragma unroll
    for (int q = 0; q < 4; ++q) {
      short8 b = *(const short8*)(wpf + ((size_t)q*KC + kc)*512 + lane*8);
      asm("v_mfma_f32_16x16x32_bf16 %0, %1, %2, %0" : "+v"(acc[q]) : "v"(a), "v"(b));
    }
  }
}

struct SP {
  const float *prev_state, *prev_belief, *actions, *nonterm, *nb, *nq;
  const bf16 *w_sa, *w_gru, *w_eb, *w_bq, *w_ebq, *w_sq;
  const float *bg, *b_sa, *b_eb, *b_bq, *b_sq;
  const bf16 *obs_c;
  float *o_bel, *o_qst, *o_qm, *o_qsd;
};

__global__ __launch_bounds__(512) void scan_k(SP p) {
  __shared__ bf16 sB[16*1024];   // bel carry
  __shared__ bf16 sD[16*1024];   // deter; after GRU: sh (0-511) + shq (512-1023)
  __shared__ bf16 sR[16*1024];   // qsa [16][320]; after eb-stage input: rnn
  const int tid = threadIdx.x, l = tid & 63, w2 = tid >> 6;   // 8 waves
  const int fl = l & 15, fg = l >> 4;
  const int rbase = blockIdx.x * 16;

  // ---- prologue: bel <- prev_belief ; qsa <- prev_state ; pad zeros once ----
  if (tid < 256) {
    const int r = tid >> 4;
    const int c0 = (tid & 15) * 64;
    const float* src = p.prev_belief + (size_t)(rbase + r)*1024 + c0;
#pragma unroll
    for (int s = 0; s < 8; ++s) {
      float4 a = *(const float4*)(src + s*8);
      float4 b = *(const float4*)(src + s*8 + 4);
      bf16 t8[8] __attribute__((aligned(16)));
      t8[0]=f2b(a.x); t8[1]=f2b(a.y); t8[2]=f2b(a.z); t8[3]=f2b(a.w);
      t8[4]=f2b(b.x); t8[5]=f2b(b.y); t8[6]=f2b(b.z); t8[7]=f2b(b.w);
      *(short8*)(sB + aoff(r, c0 + s*8, 1024)) = *(const short8*)t8;
    }
    const int c1 = (tid & 15) * 16;
    const float* sq2 = p.prev_state + (size_t)(rbase + r)*256 + c1;
#pragma unroll
    for (int s = 0; s < 2; ++s) {
      float4 a = *(const float4*)(sq2 + s*8);
      float4 b = *(const float4*)(sq2 + s*8 + 4);
      bf16 t8[8] __attribute__((aligned(16)));
      t8[0]=f2b(a.x); t8[1]=f2b(a.y); t8[2]=f2b(a.z); t8[3]=f2b(a.w);
      t8[4]=f2b(b.x); t8[5]=f2b(b.y); t8[6]=f2b(b.z); t8[7]=f2b(b.w);
      *(short8*)(sR + aoff(r, c1 + s*8, 320)) = *(const short8*)t8;
    }
  } else if (tid < 320) {
    const int r = (tid-256) >> 2, c0 = 288 + ((tid-256)&3)*8;
    bf16 z8[8] __attribute__((aligned(16))) = {};
    *(short8*)(sR + aoff(r, c0, 320)) = *(const short8*)z8;   // pad, written once
  }
  __syncthreads();

#pragma unroll 1
  for (int t = 0; t < 64; ++t) {
    // ---- S1 prep: actions -> qsa cols 256..287 ----
    if (tid < 128) {
      const int r = tid >> 3, cc = (tid & 7) * 4;
      float4 a = *(const float4*)(p.actions + (size_t)(t*512 + rbase + r)*32 + cc);
      sR[aoff(r, 256+cc,   320)] = f2b(a.x);
      sR[aoff(r, 256+cc+1, 320)] = f2b(a.y);
      sR[aoff(r, 256+cc+2, 320)] = f2b(a.z);
      sR[aoff(r, 256+cc+3, 320)] = f2b(a.w);
    }
    __syncthreads();
    // ---- S1: deter = relu(qsa @ Wsa' + b_sa), N=1024: 8 frags/wave ----
    {
      auto aq = [&](int c){ return *(const short8*)(sR + aoff(fl, c + fg*8, 320)); };
#pragma unroll 1
      for (int g = 0; g < 2; ++g) {
        f32x4 acc[4] = {};
        const int f0 = w2*8 + g*4;
        gemm4<10>(acc, p.w_sa + (size_t)f0*10*512, l, aq);
#pragma unroll
        for (int q = 0; q < 4; ++q) {
          const int col = (f0+q)*16 + fl;
          const float bv = p.b_sa[col];
#pragma unroll
          for (int rr = 0; rr < 4; ++rr) {
            float v = acc[q][rr] + bv;
            sD[aoff(fg*4+rr, col, 1024)] = f2b(v > 0.f ? v : 0.f);
          }
        }
      }
    }
    __syncthreads();
    // ---- S2: GRU, no-pad pack: per (jt,kc) 6 frags [r_lo,z_lo,i,r_hi,z_hi,h] ----
    {
#pragma unroll 1
      for (int jj = 0; jj < 8; ++jj) {
        const int jt = w2*8 + jj;
        const bf16* base = p.w_gru + (size_t)jt*32*6*512 + l*8;
        f32x4 ar_ = {}, az_ = {}, ai_ = {}, ah_ = {};
        short8 b0[6], b1[6];
#pragma unroll
        for (int s = 0; s < 6; ++s) b0[s] = *(const short8*)(base + (size_t)s*512);
#pragma unroll 1
        for (int kc = 0; kc < 32; kc += 2) {
#pragma unroll
          for (int s = 0; s < 6; ++s)
            b1[s] = *(const short8*)(base + (size_t)((kc+1)*6 + s)*512);
          short8 ad = *(const short8*)(sD + aoff(fl, kc*32 + fg*8, 1024));
          short8 ab = *(const short8*)(sB + aoff(fl, kc*32 + fg*8, 1024));
          asm("v_mfma_f32_16x16x32_bf16 %0, %1, %2, %0" : "+v"(ar_) : "v"(ad), "v"(b0[0]));
          asm("v_mfma_f32_16x16x32_bf16 %0, %1, %2, %0" : "+v"(az_) : "v"(ad), "v"(b0[1]));
          asm("v_mfma_f32_16x16x32_bf16 %0, %1, %2, %0" : "+v"(ai_) : "v"(ad), "v"(b0[2]));
          asm("v_mfma_f32_16x16x32_bf16 %0, %1, %2, %0" : "+v"(ar_) : "v"(ab), "v"(b0[3]));
          asm("v_mfma_f32_16x16x32_bf16 %0, %1, %2, %0" : "+v"(az_) : "v"(ab), "v"(b0[4]));
          asm("v_mfma_f32_16x16x32_bf16 %0, %1, %2, %0" : "+v"(ah_) : "v"(ab), "v"(b0[5]));
          if (kc + 2 < 32) {
#pragma unroll
            for (int s = 0; s < 6; ++s)
              b0[s] = *(const short8*)(base + (size_t)((kc+2)*6 + s)*512);
          }
          ad = *(const short8*)(sD + aoff(fl, (kc+1)*32 + fg*8, 1024));
          ab = *(const short8*)(sB + aoff(fl, (kc+1)*32 + fg*8, 1024));
          asm("v_mfma_f32_16x16x32_bf16 %0, %1, %2, %0" : "+v"(ar_) : "v"(ad), "v"(b1[0]));
          asm("v_mfma_f32_16x16x32_bf16 %0, %1, %2, %0" : "+v"(az_) : "v"(ad), "v"(b1[1]));
          asm("v_mfma_f32_16x16x32_bf16 %0, %1, %2, %0" : "+v"(ai_) : "v"(ad), "v"(b1[2]));
          asm("v_mfma_f32_16x16x32_bf16 %0, %1, %2, %0" : "+v"(ar_) : "v"(ab), "v"(b1[3]));
          asm("v_mfma_f32_16x16x32_bf16 %0, %1, %2, %0" : "+v"(az_) : "v"(ab), "v"(b1[4]));
          asm("v_mfma_f32_16x16x32_bf16 %0, %1, %2, %0" : "+v"(ah_) : "v"(ab), "v"(b1[5]));
        }
        const int j = jt*16 + fl;
        const float g0 = p.bg[j], g1 = p.bg[1024+j], g2 = p.bg[2048+j], g3 = p.bg[3072+j];
#pragma unroll
        for (int rr = 0; rr < 4; ++rr) {
          const int row = fg*4 + rr;
          const float r_ = sg_f(ar_[rr] + g0);
          const float z_ = sg_f(az_[rr] + g1);
          const float nn = tanhf((ai_[rr] + g2) + r_*(ah_[rr] + g3));
          const float h = b2f(sB[aoff(row, j, 1024)]);
          sR[aoff(row, j, 1024)] = f2b((1.f - z_)*nn + z_*h);
        }
      }
    }
    __syncthreads();
    // ---- S3: sh = relu(rnn @ Web' + b_eb), N=512: 4 frags/wave ----
    {
      auto ar = [&](int c){ return *(const short8*)(sR + aoff(fl, c + fg*8, 1024)); };
      f32x4 acc[4] = {};
      const int f0 = w2*4;
      gemm4<32>(acc, p.w_eb + (size_t)f0*32*512, l, ar);
#pragma unroll
      for (int q = 0; q < 4; ++q) {
        const int col = (f0+q)*16 + fl;
        const float bv = p.b_eb[col];
#pragma unroll
        for (int rr = 0; rr < 4; ++rr) {
          float v = acc[q][rr] + bv;
          sD[aoff(fg*4+rr, col, 1024)] = f2b(v > 0.f ? v : 0.f);
        }
      }
    }
    __syncthreads();
    // ---- S4: belief head (paired Wbq'): 16 frags/wave ----
    {
      auto as = [&](int c){ return *(const short8*)(sD + aoff(fl, c + fg*8, 1024)); };
      const float* nbt = p.nb + (size_t)(t*512 + rbase)*1024;
      float* obt = p.o_bel + (size_t)(t*512 + rbase)*1024;
#pragma unroll 1
      for (int g = 0; g < 4; ++g) {
        f32x4 acc[4] = {};
        const int f0 = w2*16 + g*4;
        gemm4<16>(acc, p.w_bq + (size_t)f0*16*512, l, as);
#pragma unroll
        for (int jj = 0; jj < 2; ++jj) {
          const int j = (w2*8 + g*2 + jj)*16 + fl;
          const float bm = p.b_bq[j], bs = p.b_bq[1024 + j];
#pragma unroll
          for (int rr = 0; rr < 4; ++rr) {
            const int row = fg*4 + rr;
            const float mean = acc[2*jj][rr] + bm;
            const float sd = sp_f(acc[2*jj+1][rr] + bs) + 0.1f;
            const float bl = mean + sd * nbt[(size_t)row*1024 + j];
            obt[(size_t)row*1024 + j] = bl;
            sB[aoff(row, j, 1024)] = f2b(bl);
          }
        }
      }
    }
    __syncthreads();
    // ---- S5: shq = relu(bel @ Webq_lo' + obs_c[t]): 4 frags/wave ----
    {
      auto ab = [&](int c){ return *(const short8*)(sB + aoff(fl, c + fg*8, 1024)); };
      const bf16* oc = p.obs_c + (size_t)(t*512 + rbase)*512;
      f32x4 acc[4] = {};
      const int f0 = w2*4;
      gemm4<32>(acc, p.w_ebq + (size_t)f0*32*512, l, ab);
#pragma unroll
      for (int q = 0; q < 4; ++q) {
        const int col = (f0+q)*16 + fl;
#pragma unroll
        for (int rr = 0; rr < 4; ++rr) {
          const int row = fg*4 + rr;
          float v = acc[q][rr] + b2f(oc[(size_t)row*512 + col]);
          sD[aoff(row, 512 + col, 1024)] = f2b(v > 0.f ? v : 0.f);
        }
      }
    }
    __syncthreads();
    // ---- S6: q head (paired Wsq'): 4 frags/wave -> outputs + next qsa ----
    {
      auto ax = [&](int c){ return *(const short8*)(sD + aoff(fl, 512 + c + fg*8, 1024)); };
      const float* nqt = p.nq + (size_t)(t*512 + rbase)*256;
      float* qm = p.o_qm  + (size_t)(t*512 + rbase)*256;
      float* qs = p.o_qsd + (size_t)(t*512 + rbase)*256;
      float* qt = p.o_qst + (size_t)(t*512 + rbase)*256;
      const float* ntp = p.nonterm + (size_t)t*512 + rbase;
      f32x4 acc[4] = {};
      const int f0 = w2*4;
      gemm4<16>(acc, p.w_sq + (size_t)f0*16*512, l, ax);
#pragma unroll
      for (int jj = 0; jj < 2; ++jj) {
        const int j = (w2*2 + jj)*16 + fl;
        const float bm = p.b_sq[j], bs = p.b_sq[256 + j];
#pragma unroll
        for (int rr = 0; rr < 4; ++rr) {
          const int row = fg*4 + rr;
          const float mean = acc[2*jj][rr] + bm;
          const float sd = sp_f(acc[2*jj+1][rr] + bs) + 0.1f;
          const float q = mean + sd * nqt[(size_t)row*256 + j];
          qm[(size_t)row*256 + j] = mean;
          qs[(size_t)row*256 + j] = sd;
          qt[(size_t)row*256 + j] = q;
          sR[aoff(row, j, 320)] = f2b(q * ntp[row]);
        }
      }
    }
    __syncthreads();
  }
}

// ===== wide-kernel helpers (R6/R7-proven) =====
__device__ __forceinline__ int lds_off(int row, int slot){ return row*64 + ((slot ^ (row & 7)) << 3); }

__device__ __forceinline__ void glds_tile(const bf16* base, int ld, bf16* buf, int w, int l) {
  const int rsub = l >> 3;
  const int slot = (l & 7) ^ rsub;
  const bf16* src = base + (size_t)(w*32 + rsub)*ld + slot*8;
#pragma unroll
  for (int i = 0; i < 4; ++i)
    __builtin_amdgcn_global_load_lds((const __attribute__((address_space(1))) void*)(src + (size_t)(i*8)*ld),
                                     (__attribute__((address_space(3))) void*)(buf + (w*32 + i*8)*64),
                                     16, 0, 0);
}
__device__ __forceinline__ void glds_tile64(const bf16* base, int ld, bf16* buf, int w, int l) {
  const int rsub = l >> 3;
  const int slot = (l & 7) ^ rsub;
  const bf16* src = base + (size_t)(w*16 + rsub)*ld + slot*8;
#pragma unroll
  for (int i = 0; i < 2; ++i)
    __builtin_amdgcn_global_load_lds((const __attribute__((address_space(1))) void*)(src + (size_t)(i*8)*ld),
                                     (__attribute__((address_space(3))) void*)(buf + (w*16 + i*8)*64),
                                     16, 0, 0);
}

__device__ __forceinline__ void mfma_tiles(f32x4 acc[4][4], const bf16* bA, const bf16* bB,
                                           int wm, int wn, int fl, int fg) {
#pragma unroll
  for (int ks = 0; ks < 2; ++ks) {
    short8 af[4], bfr[4];
#pragma unroll
    for (int i = 0; i < 4; ++i)
      af[i] = *(const short8*)(bA + lds_off(wm*64 + i*16 + fl, ks*4 + fg));
#pragma unroll
    for (int i = 0; i < 4; ++i)
      bfr[i] = *(const short8*)(bB + lds_off(wn*64 + i*16 + fl, ks*4 + fg));
#pragma unroll
    for (int mf = 0; mf < 4; ++mf)
#pragma unroll
      for (int nf = 0; nf < 4; ++nf)
        asm("v_mfma_f32_16x16x32_bf16 %0, %1, %2, %0"
            : "+v"(acc[mf][nf]) : "v"(af[mf]), "v"(bfr[nf]));
  }
}

template<bool RELU>
__device__ void wide_f32_gemm(const float* A, int lda, const bf16* Bw, int ldb, int K,
                              const float* bias, bf16* dst, int ldc) {
  __shared__ bf16 sA0[8192];
  __shared__ bf16 sB0[8192];
  const int tid = threadIdx.x, l = tid & 63, w = tid >> 6;
  const int wm = w >> 1, wn = w & 1, fl = l & 15, fg = l >> 4;
  const int rb = ((int)blockIdx.x >> 2) << 7, nt = blockIdx.x & 3;
  f32x4 acc[4][4] = {};
#pragma unroll 1
  for (int ki = 0; ki < (K >> 6); ++ki) {
    const int k0 = ki << 6;
    glds_tile(Bw + (size_t)(nt*128)*ldb + k0, ldb, sB0, w, l);
#pragma unroll
    for (int i = 0; i < 4; ++i) {
      const int sid = tid + (i << 8);
      const int row = sid >> 3, s = sid & 7;
      const float* src = A + (size_t)(rb + row)*lda + k0 + s*8;
      float4 a = ((const float4*)src)[0], b = ((const float4*)src)[1];
      bf16 t8[8] __attribute__((aligned(16)));
      t8[0]=f2b(a.x); t8[1]=f2b(a.y); t8[2]=f2b(a.z); t8[3]=f2b(a.w);
      t8[4]=f2b(b.x); t8[5]=f2b(b.y); t8[6]=f2b(b.z); t8[7]=f2b(b.w);
      *(short8*)(sA0 + lds_off(row, s)) = *(const short8*)t8;
    }
    asm volatile("s_waitcnt vmcnt(0) lgkmcnt(0)" ::: "memory");
    __builtin_amdgcn_s_barrier();
    mfma_tiles(acc, sA0, sB0, wm, wn, fl, fg);
    __builtin_amdgcn_s_barrier();
  }
#pragma unroll
  for (int mf = 0; mf < 4; ++mf)
#pragma unroll
    for (int nf = 0; nf < 4; ++nf) {
      const int col = nt*128 + wn*64 + nf*16 + fl;
      const float bv = bias[col];
#pragma unroll
      for (int r = 0; r < 4; ++r) {
        const int row = rb + wm*64 + mf*16 + fg*4 + r;
        float v = acc[mf][nf][r] + bv;
        if (RELU) v = v > 0.f ? v : 0.f;
        dst[(size_t)row*ldc + col] = f2b(v);
      }
    }
}

__global__ __launch_bounds__(256) void obsc_k(const float* obs, const bf16* webqh,
                                              const float* b_ebq, bf16* obs_c) {
  wide_f32_gemm<false>(obs, 1024, webqh, 1024, 1024, b_ebq, obs_c, 512);
}
__global__ __launch_bounds__(256) void shp_k(const float* bel, const bf16* webp,
                                             const float* b_ebp, bf16* shp) {
  wide_f32_gemm<true>(bel, 1024, webp, 1024, 1024, b_ebp, shp, 512);
}

__global__ __launch_bounds__(256) void phead_k(const bf16* shp, const bf16* wsp,
    const float* b_sp, const float* np, float* o_pm, float* o_psd, float* o_pst) {
  __shared__ bf16 stA[64*64];
  __shared__ bf16 stB[128*64];
  __shared__ float stash[64*256];
  const int tid = threadIdx.x, l = tid & 63, w = tid >> 6;
  const int wm = w >> 1, wn = w & 1, fl = l & 15, fg = l >> 4;
  const int R0 = blockIdx.x * 64;
#pragma unroll 1
  for (int nt = 0; nt < 4; ++nt) {
    f32x4 acc[2][4] = {};
#pragma unroll 1
    for (int kc = 0; kc < 8; ++kc) {
      glds_tile64(shp + (size_t)R0*512 + kc*64, 512, stA, w, l);
      glds_tile(wsp + (size_t)(nt*128)*512 + kc*64, 512, stB, w, l);
      asm volatile("s_waitcnt vmcnt(0)" ::: "memory");
      __builtin_amdgcn_s_barrier();
#pragma unroll
      for (int ks = 0; ks < 2; ++ks) {
        short8 af[2], bfr[4];
#pragma unroll
        for (int mf = 0; mf < 2; ++mf)
          af[mf] = *(const short8*)(stA + lds_off(wm*32 + mf*16 + fl, ks*4 + fg));
#pragma unroll
        for (int nf = 0; nf < 4; ++nf)
          bfr[nf] = *(const short8*)(stB + lds_off(wn*64 + nf*16 + fl, ks*4 + fg));
#pragma unroll
        for (int mf = 0; mf < 2; ++mf)
#pragma unroll
          for (int nf = 0; nf < 4; ++nf)
            asm("v_mfma_f32_16x16x32_bf16 %0, %1, %2, %0"
                : "+v"(acc[mf][nf]) : "v"(af[mf]), "v"(bfr[nf]));
      }
      __builtin_amdgcn_s_barrier();
    }
#pragma unroll
    for (int mf = 0; mf < 2; ++mf)
#pragma unroll
      for (int gg = 0; gg < 2; ++gg) {
        const int j = nt*64 + (wn*2 + gg)*16 + fl;
        const float bm = b_sp[j], bs = b_sp[256 + j];
#pragma unroll
        for (int rr = 0; rr < 4; ++rr) {
          const int rl = wm*32 + mf*16 + fg*4 + rr;
          const float mean = acc[mf][2*gg][rr] + bm;
          const float sd = sp_f(acc[mf][2*gg+1][rr] + bs) + 0.1f;
          o_pm [(size_t)(R0+rl)*256 + j] = mean;
          o_psd[(size_t)(R0+rl)*256 + j] = sd;
          stash[rl*256 + j] = mean + sd * np[(size_t)(R0+rl)*256 + j];
        }
      }
  }
  __syncthreads();
#pragma unroll 1
  for (int i = tid; i < 4096; i += 256) {
    const int r = i >> 6, c4 = (i & 63) << 2;
    *(float4*)(o_pst + (size_t)(R0+r)*256 + c4) = *(const float4*)(stash + r*256 + c4);
  }
}

// ===== prep: fragment-packing kernels =====
__global__ __launch_bounds__(256) void k_pack(const float* __restrict__ src, bf16* __restrict__ dst,
    int NF, int KC, int Ksrc, int ldsrc, int rowoff, int pair, int halfN) {
  const int idx = blockIdx.x*256 + threadIdx.x;
  if (idx >= NF*KC*64) return;
  const int lane = idx & 63, kc = (idx >> 6) % KC, fi = idx / (64*KC);
  int col;
  if (pair) { const int jt = fi >> 1, pp = fi & 1; col = pp*halfN + jt*16 + (lane & 15); }
  else col = fi*16 + (lane & 15);
  const int kb = kc*32 + (lane >> 4)*8;
  bf16 t8[8] __attribute__((aligned(16)));
#pragma unroll
  for (int e = 0; e < 8; ++e) {
    const int k = kb + e;
    t8[e] = f2b(k < Ksrc ? src[(size_t)col*ldsrc + rowoff + k] : 0.f);
  }
  *(short8*)(dst + (size_t)idx*8) = *(const short8*)t8;
}

// GRU no-pad pack: unit u = ((jt*32+kc)*6+slot)*64+lane; slots:
// 0:Wih_r 1:Wih_z 2:Wih_n 3:Whh_r 4:Whh_z 5:Whh_n ; k in [0,1024)
__global__ __launch_bounds__(256) void k_gru_pack6(const float* __restrict__ Wih,
    const float* __restrict__ Whh, bf16* __restrict__ dst) {
  const int idx = blockIdx.x*256 + threadIdx.x;
  if (idx >= 786432) return;
  const int lane = idx & 63;
  const int rest = idx >> 6;
  const int slot = rest % 6;
  const int tkc  = rest / 6;
  const int kc = tkc & 31, jt = tkc >> 5;
  const int j = jt*16 + (lane & 15);
  const int kb = kc*32 + (lane >> 4)*8;
  const float* src;
  if (slot == 0)      src = Wih + (size_t)j*1024;
  else if (slot == 1) src = Wih + (size_t)(1024+j)*1024;
  else if (slot == 2) src = Wih + (size_t)(2048+j)*1024;
  else if (slot == 3) src = Whh + (size_t)j*1024;
  else if (slot == 4) src = Whh + (size_t)(1024+j)*1024;
  else                src = Whh + (size_t)(2048+j)*1024;
  bf16 t8[8] __attribute__((aligned(16)));
#pragma unroll
  for (int e = 0; e < 8; ++e) t8[e] = f2b(src[kb + e]);
  *(short8*)(dst + (size_t)idx*8) = *(const short8*)t8;
}

__global__ __launch_bounds__(256) void k_cvt8(const float* __restrict__ s, bf16* __restrict__ d, int n8) {
  const int i = blockIdx.x*256 + threadIdx.x;
  if (i >= n8) return;
  float4 a = ((const float4*)s)[i*2], b = ((const float4*)s)[i*2+1];
  bf16 t8[8] __attribute__((aligned(16)));
  t8[0]=f2b(a.x); t8[1]=f2b(a.y); t8[2]=f2b(a.z); t8[3]=f2b(a.w);
  t8[4]=f2b(b.x); t8[5]=f2b(b.y); t8[6]=f2b(b.z); t8[7]=f2b(b.w);
  ((short8*)d)[i] = *(const short8*)t8;
}
__global__ __launch_bounds__(256) void k_cvthalf(const float* __restrict__ s, bf16* __restrict__ d) {
  const int i = blockIdx.x*256 + threadIdx.x;
  if (i >= 65536) return;
  const int r = i >> 7, c8 = (i & 127)*8;
  const float* sp2 = s + (size_t)r*2048 + 1024 + c8;
  float4 a = ((const float4*)sp2)[0], b = ((const float4*)sp2)[1];
  bf16 t8[8] __attribute__((aligned(16)));
  t8[0]=f2b(a.x); t8[1]=f2b(a.y); t8[2]=f2b(a.z); t8[3]=f2b(a.w);
  t8[4]=f2b(b.x); t8[5]=f2b(b.y); t8[6]=f2b(b.z); t8[7]=f2b(b.w);
  *(short8*)(d + (size_t)i*8) = *(const short8*)t8;
}
__global__ __launch_bounds__(256) void k_pair(const float* __restrict__ src, bf16* __restrict__ dst,
                                              int halfN, int n) {
  const int idx = blockIdx.x*256 + threadIdx.x;
  if (idx >= n) return;
  const int rp = idx >> 7;
  const int c4 = (idx & 127) << 2;
  const int nt = rp >> 7, id = rp & 127;
  const int pb = (id >> 5) & 3, comp = (id >> 4) & 1, fl2 = id & 15;
  const int j = nt*64 + pb*16 + fl2;
  const int srow = comp*halfN + j;
  float4 v = *(const float4*)(src + (size_t)srow*512 + c4);
  bf16 t4[4] __attribute__((aligned(8)));
  t4[0]=f2b(v.x); t4[1]=f2b(v.y); t4[2]=f2b(v.z); t4[3]=f2b(v.w);
  *(uint2*)(dst + (size_t)rp*512 + c4) = *(const uint2*)t4;
}
__global__ __launch_bounds__(256) void k_bg(const float* b_ih, const float* b_hh, float* bg) {
  const int i = blockIdx.x*256 + threadIdx.x;
  if (i >= 4096) return;
  const int g = i >> 10, j = i & 1023;
  float v;
  if (g == 0) v = b_ih[j] + b_hh[j];
  else if (g == 1) v = b_ih[1024+j] + b_hh[1024+j];
  else if (g == 2) v = b_ih[2048+j];
  else v = b_hh[2048+j];
  bg[i] = v;
}

extern "C" void kernel_launch(void* const* d_in, const int* in_sizes, int n_in,
                              void* d_out, int out_size, void* d_ws, size_t ws_size,
                              hipStream_t stream) {
  const float* prev_state   = (const float*)d_in[0];
  const float* prev_belief  = (const float*)d_in[1];
  const float* actions      = (const float*)d_in[2];
  const float* observations = (const float*)d_in[3];
  const float* nonterm      = (const float*)d_in[4];
  const float* noise_belief = (const float*)d_in[5];
  const float* noise_prior  = (const float*)d_in[6];
  const float* noise_post   = (const float*)d_in[7];
  const float* W_sa  = (const float*)d_in[8];  const float* b_sa  = (const float*)d_in[9];
  const float* W_ih  = (const float*)d_in[10]; const float* b_ih  = (const float*)d_in[11];
  const float* W_hh  = (const float*)d_in[12]; const float* b_hh  = (const float*)d_in[13];
  const float* W_eb  = (const float*)d_in[14]; const float* b_eb  = (const float*)d_in[15];
  const float* W_bq  = (const float*)d_in[16]; const float* b_bq  = (const float*)d_in[17];
  const float* W_ebp = (const float*)d_in[18]; const float* b_ebp = (const float*)d_in[19];
  const float* W_sp  = (const float*)d_in[20]; const float* b_sp  = (const float*)d_in[21];
  const float* W_ebq = (const float*)d_in[22]; const float* b_ebq = (const float*)d_in[23];
  const float* W_sq  = (const float*)d_in[24]; const float* b_sq  = (const float*)d_in[25];

  float* out = (float*)d_out;
  char* ws = (char*)d_ws;

  // ws layout
  float* bg   = (float*)ws;                  // [4096] f32
  bf16* wb    = (bf16*)(ws + 16384);
  bf16* w_sa  = wb;                          // 64f x 10kc   =   327,680
  bf16* w_gru = wb + 327680;                 // 64jt x 32kc x 6 = 6,291,456
  bf16* w_eb  = wb + 6619136;                // 32f x 32kc   =   524,288
  bf16* w_bq  = wb + 7143424;                // 128f x 16kc  = 1,048,576
  bf16* w_ebq = wb + 8192000;                // 32f x 32kc   =   524,288
  bf16* w_sq  = wb + 8716288;                // 32f x 16kc   =   262,144
  bf16* w_ebqh= wb + 8978432;                // old [512][1024] 524,288
  bf16* w_ebp = wb + 9502720;                // old [512][1024] 524,288
  bf16* w_sp  = wb + 10027008;               // old-pair [512][512] 262,144

  float* o_bel = out;
  float* o_pst = out + 33554432;
  float* o_pm  = out + 41943040;
  float* o_psd = out + 50331648;
  float* o_qst = out + 58720256;
  float* o_qm  = out + 67108864;
  float* o_qsd = out + 75497472;
  bf16* obs_c = (bf16*)o_pm;    // [32768][512] bf16 (dead until p_mean written)
  bf16* shp   = (bf16*)o_pst;   // [32768][512] bf16 (overwritten row-locally)

  // ---- prep ----
  k_bg       <<<16,   256, 0, stream>>>(b_ih, b_hh, bg);
  k_pack     <<<160,  256, 0, stream>>>(W_sa, w_sa, 64, 10, 288, 288, 0, 0, 0);
  k_gru_pack6<<<3072, 256, 0, stream>>>(W_ih, W_hh, w_gru);
  k_pack     <<<256,  256, 0, stream>>>(W_eb, w_eb, 32, 32, 1024, 1024, 0, 0, 0);
  k_pack     <<<512,  256, 0, stream>>>(W_bq, w_bq, 128, 16, 512, 512, 0, 1, 1024);
  k_pack     <<<256,  256, 0, stream>>>(W_ebq, w_ebq, 32, 32, 1024, 2048, 0, 0, 0);
  k_pack     <<<128,  256, 0, stream>>>(W_sq, w_sq, 32, 16, 512, 512, 0, 1, 256);
  k_cvthalf  <<<256,  256, 0, stream>>>(W_ebq, w_ebqh);
  k_cvt8     <<<256,  256, 0, stream>>>(W_ebp, w_ebp, 65536);
  k_pair     <<<256,  256, 0, stream>>>(W_sp, w_sp, 256, 65536);

  // ---- prologue: obs contribution ----
  obsc_k<<<1024, 256, 0, stream>>>(observations, w_ebqh, b_ebq, obs_c);

  // ---- scan: 32 zero-sync blocks x 512 threads ----
  SP p;
  p.prev_state = prev_state; p.prev_belief = prev_belief; p.actions = actions;
  p.nonterm = nonterm; p.nb = noise_belief; p.nq = noise_post;
  p.w_sa = w_sa; p.w_gru = w_gru; p.w_eb = w_eb; p.w_bq = w_bq; p.w_ebq = w_ebq; p.w_sq = w_sq;
  p.bg = bg; p.b_sa = b_sa; p.b_eb = b_eb; p.b_bq = b_bq; p.b_sq = b_sq;
  p.obs_c = obs_c;
  p.o_bel = o_bel; p.o_qst = o_qst; p.o_qm = o_qm; p.o_qsd = o_qsd;
  scan_k<<<32, 512, 0, stream>>>(p);

  // ---- prior branch ----
  shp_k  <<<1024, 256, 0, stream>>>(o_bel, w_ebp, b_ebp, shp);
  phead_k<<<512,  256, 0, stream>>>(shp, w_sp, b_sp, noise_prior, o_pm, o_psd, o_pst);
}